// Round 3
// baseline (9672.607 us; speedup 1.0000x reference)
//
#include <hip/hip_runtime.h>

// ---------------------------------------------------------------------------
// Complex GEMM: Out[n][j] = epilogue( sum_k X[n][k] * (Wr[j][k] + i*Wi[j][k]) + b[j] )
// X: REAL_IN ? float [N,K] real : float2 [N,K] complex
// W: float [J,K] row-major. Out: float2 [N,J].
// Epilogue: optional complex-relu; optional multiply by F = exp(-i t)*(1-exp(-i t/2))
// (time factor with the downstream mix coefficient folded in).
// ---------------------------------------------------------------------------
template<int K, int J, bool REAL_IN, bool CRELU, bool TSCALE>
__global__ __launch_bounds__(256) void cgemm_kernel(
    const void* __restrict__ Xv,
    const float* __restrict__ Wr,
    const float* __restrict__ Wi,
    const float* __restrict__ br,
    const float* __restrict__ bi,
    const float* __restrict__ trp,
    const float* __restrict__ tip,
    float2* __restrict__ Out, int nNodes)
{
    constexpr int TN   = 16;        // nodes per block
    constexpr int KC   = 32;        // K chunk (fp32 LDS budget)
    constexpr int WROW = KC + 1;    // 33: bank = (33j+kk)%32 = (j+kk)%32 -> conflict-free scalar reads
    constexpr int NG   = 256 / J;   // node groups
    constexpr int NPG  = TN / NG;   // nodes per thread
    static_assert(K % KC == 0, "K % KC");

    __shared__ float sWr[J * WROW];
    __shared__ float sWi[J * WROW];
    __shared__ float sX[TN * KC * (REAL_IN ? 1 : 2)];

    const int tid = threadIdx.x;
    const int j   = tid % J;
    const int g   = tid / J;
    const int n0  = blockIdx.x * TN;

    float accR[NPG], accI[NPG];
    #pragma unroll
    for (int i = 0; i < NPG; ++i) { accR[i] = 0.f; accI[i] = 0.f; }

    for (int kc = 0; kc < K; kc += KC) {
        // ---- stage W chunk (coalesced float4 global loads, scalar LDS stores) ----
        {
            constexpr int TOT = J * (KC / 4);
            for (int idx = tid; idx < TOT; idx += 256) {
                int row = idx / (KC / 4);
                int col = (idx % (KC / 4)) * 4;
                float4 r  = *(const float4*)(Wr + (size_t)row * K + kc + col);
                float4 im = *(const float4*)(Wi + (size_t)row * K + kc + col);
                float* pr = sWr + row * WROW + col;
                float* pi = sWi + row * WROW + col;
                pr[0] = r.x;  pr[1] = r.y;  pr[2] = r.z;  pr[3] = r.w;
                pi[0] = im.x; pi[1] = im.y; pi[2] = im.z; pi[3] = im.w;
            }
        }
        // ---- stage X chunk ----
        if constexpr (REAL_IN) {
            const float* X = (const float*)Xv;
            constexpr int TOT = TN * (KC / 4);
            for (int idx = tid; idx < TOT; idx += 256) {
                int row = idx / (KC / 4);
                int col = (idx % (KC / 4)) * 4;
                int n = n0 + row;
                float4 f = make_float4(0.f, 0.f, 0.f, 0.f);
                if (n < nNodes)
                    f = *(const float4*)(X + (size_t)n * K + kc + col);
                *(float4*)(sX + row * KC + col) = f;
            }
        } else {
            const float2* X = (const float2*)Xv;
            constexpr int TOT = TN * (KC / 2);
            for (int idx = tid; idx < TOT; idx += 256) {
                int row = idx / (KC / 2);
                int col = (idx % (KC / 2)) * 2;   // complex index
                int n = n0 + row;
                float4 f = make_float4(0.f, 0.f, 0.f, 0.f);
                if (n < nNodes)
                    f = *(const float4*)(X + (size_t)n * K + kc + col);
                *(float4*)(sX + (row * KC + col) * 2) = f;
            }
        }
        __syncthreads();

        // ---- compute ----
        if constexpr (REAL_IN) {
            #pragma unroll
            for (int kk = 0; kk < KC; kk += 4) {
                const float* wrp = sWr + j * WROW + kk;
                const float* wip = sWi + j * WROW + kk;
                float wr0 = wrp[0], wr1 = wrp[1], wr2 = wrp[2], wr3 = wrp[3];
                float wi0 = wip[0], wi1 = wip[1], wi2 = wip[2], wi3 = wip[3];
                #pragma unroll
                for (int nn = 0; nn < NPG; ++nn) {
                    int n = g * NPG + nn;
                    float4 x4 = *(const float4*)(sX + n * KC + kk);
                    accR[nn] += x4.x * wr0 + x4.y * wr1 + x4.z * wr2 + x4.w * wr3;
                    accI[nn] += x4.x * wi0 + x4.y * wi1 + x4.z * wi2 + x4.w * wi3;
                }
            }
        } else {
            #pragma unroll
            for (int kk = 0; kk < KC; kk += 2) {
                const float* wrp = sWr + j * WROW + kk;
                const float* wip = sWi + j * WROW + kk;
                float wr0 = wrp[0], wr1 = wrp[1];
                float wi0 = wip[0], wi1 = wip[1];
                #pragma unroll
                for (int nn = 0; nn < NPG; ++nn) {
                    int n = g * NPG + nn;
                    float4 x = *(const float4*)(sX + (n * KC + kk) * 2);  // 2 complex
                    accR[nn] += x.x * wr0 - x.y * wi0;
                    accI[nn] += x.x * wi0 + x.y * wr0;
                    accR[nn] += x.z * wr1 - x.w * wi1;
                    accI[nn] += x.z * wi1 + x.w * wr1;
                }
            }
        }
        __syncthreads();
    }

    // ---- epilogue ----
    float bre = br[j];
    float bim = bi[j];
    float Fr = 1.f, Fi = 0.f;
    if constexpr (TSCALE) {
        float tr = trp[0], ti = tip[0];
        float er  = expf(ti);                 // exp(-i*(tr+i*ti)) = e^{ti}(cos tr - i sin tr)
        float tfr =  er * cosf(tr);
        float tfi = -er * sinf(tr);
        float eh  = expf(0.5f * ti);          // ef = exp(-i*t*0.5)
        float efr =  eh * cosf(0.5f * tr);
        float efi = -eh * sinf(0.5f * tr);
        float omr = 1.f - efr, omi = -efi;    // (1 - ef)
        Fr = tfr * omr - tfi * omi;           // F = tf * (1-ef)
        Fi = tfr * omi + tfi * omr;
    }
    #pragma unroll
    for (int nn = 0; nn < NPG; ++nn) {
        int n = n0 + g * NPG + nn;
        if (n >= nNodes) continue;
        float a = accR[nn] + bre;
        float b = accI[nn] + bim;
        if constexpr (CRELU) { a = fmaxf(a, 0.f); b = fmaxf(b, 0.f); }
        if constexpr (TSCALE) {
            float na = a * Fr - b * Fi;
            float nb = a * Fi + b * Fr;
            a = na; b = nb;
        }
        Out[(size_t)n * J + j] = make_float2(a, b);
    }
}

// ---------------------------------------------------------------------------
// In-place complex scale by ef = exp(-i*t*0.5):  buf[g] *= ef
// ---------------------------------------------------------------------------
__global__ __launch_bounds__(256) void scale_kernel(
    float2* __restrict__ buf,
    const float* __restrict__ trp, const float* __restrict__ tip,
    int total)
{
    int gid = blockIdx.x * 256 + threadIdx.x;
    if (gid >= total) return;
    float tr = trp[0], ti = tip[0];
    float eh  = expf(0.5f * ti);
    float efr =  eh * cosf(0.5f * tr);
    float efi = -eh * sinf(0.5f * tr);
    float2 v = buf[gid];
    buf[gid] = make_float2(v.x * efr - v.y * efi, v.x * efi + v.y * efr);
}

// ---------------------------------------------------------------------------
// Edge scatter: acc[dst] += m[src].  LOGCP = log2(float4 chunks per node row).
// Consecutive threads share an edge -> index loads are wave-broadcast.
// Bounds-guarded: bad indices skip instead of faulting.
// ---------------------------------------------------------------------------
template<int LOGCP>
__global__ __launch_bounds__(256) void scatter_kernel(
    const float4* __restrict__ m, const int* __restrict__ src,
    const int* __restrict__ dst, float* __restrict__ acc, int E, int nNodes)
{
    unsigned int gid = blockIdx.x * 256u + threadIdx.x;
    unsigned int e = gid >> LOGCP;
    unsigned int c = gid & ((1u << LOGCP) - 1u);
    if (e >= (unsigned int)E) return;
    int s = src[e], d = dst[e];
    if ((unsigned)s >= (unsigned)nNodes || (unsigned)d >= (unsigned)nNodes) return;
    constexpr int CP = 1 << LOGCP;
    float4 v = m[(size_t)s * CP + c];
    float* out = acc + ((size_t)d * CP + c) * 4;
    unsafeAtomicAdd(out + 0, v.x);
    unsafeAtomicAdd(out + 1, v.y);
    unsafeAtomicAdd(out + 2, v.z);
    unsafeAtomicAdd(out + 3, v.w);
}

// abs + per-graph segment sum over final features (D_OUT = 64, d = lane)
__global__ __launch_bounds__(256) void abs_reduce_kernel(
    const float2* __restrict__ x2, const int* __restrict__ batch,
    float* __restrict__ sums, int nNodes)
{
    int gid = blockIdx.x * 256 + threadIdx.x;
    int n = gid >> 6, d = gid & 63;
    if (n >= nNodes) return;
    float2 z = x2[gid];
    float a = sqrtf(z.x * z.x + z.y * z.y);
    unsigned g = (unsigned)batch[n];
    if (g < 64u) unsafeAtomicAdd(&sums[g * 64 + d], a);
}

__global__ __launch_bounds__(256) void counts_kernel(
    const int* __restrict__ batch, float* __restrict__ counts, int nNodes)
{
    int n = blockIdx.x * 256 + threadIdx.x;
    if (n >= nNodes) return;
    unsigned g = (unsigned)batch[n];
    if (g < 64u) unsafeAtomicAdd(&counts[g], 1.0f);
}

// per-graph mean + log_softmax, one wave per graph
__global__ __launch_bounds__(64) void finalize_kernel(
    const float* __restrict__ sums, const float* __restrict__ counts,
    float* __restrict__ out)
{
    int g = blockIdx.x, d = threadIdx.x;
    float c = fmaxf(counts[g], 1.0f);
    float m = sums[g * 64 + d] / c;
    float mx = m;
    #pragma unroll
    for (int o = 32; o > 0; o >>= 1) mx = fmaxf(mx, __shfl_xor(mx, o, 64));
    float e = expf(m - mx);
    float s = e;
    #pragma unroll
    for (int o = 32; o > 0; o >>= 1) s += __shfl_xor(s, o, 64);
    out[g * 64 + d] = m - mx - logf(s);
}

extern "C" void kernel_launch(void* const* d_in, const int* in_sizes, int n_in,
                              void* d_out, int out_size, void* d_ws, size_t ws_size,
                              hipStream_t stream)
{
    const float* x   = (const float*)d_in[0];
    const float* W0r = (const float*)d_in[1];
    const float* W0i = (const float*)d_in[2];
    const float* b0r = (const float*)d_in[3];
    const float* b0i = (const float*)d_in[4];
    const float* M0r = (const float*)d_in[5];
    const float* M0i = (const float*)d_in[6];
    const float* c0r = (const float*)d_in[7];
    const float* c0i = (const float*)d_in[8];
    const float* t0r = (const float*)d_in[9];
    const float* t0i = (const float*)d_in[10];
    const float* W1r = (const float*)d_in[11];
    const float* W1i = (const float*)d_in[12];
    const float* b1r = (const float*)d_in[13];
    const float* b1i = (const float*)d_in[14];
    const float* M1r = (const float*)d_in[15];
    const float* M1i = (const float*)d_in[16];
    const float* c1r = (const float*)d_in[17];
    const float* c1i = (const float*)d_in[18];
    const float* t1r = (const float*)d_in[19];
    const float* t1i = (const float*)d_in[20];
    const int* edge  = (const int*)d_in[21];
    const int* batch = (const int*)d_in[22];

    const int N = in_sizes[0] / 128;
    const int E = in_sizes[21] / 2;
    const int* src = edge;
    const int* dst = edge + E;

    // workspace layout (floats): bufA, bufB each N*256; then sums(4096)+counts(64)
    // total = 2*N*256*4 B = 204.8 MB (+16.6 KB)
    float* bufA   = (float*)d_ws;
    float* bufB   = bufA + (size_t)N * 256;
    float* sums   = bufB + (size_t)N * 256;
    float* counts = sums + 4096;

    const int gemmGrid = (N + 15) / 16;

    // ---- layer 0 ----
    // h0 = crelu(x @ W0^T + b0)                                  -> bufA [N,128]c
    cgemm_kernel<128,128,true,true,false><<<gemmGrid, 256, 0, stream>>>(
        x, W0r, W0i, b0r, b0i, nullptr, nullptr, (float2*)bufA, N);
    // m0'' = (h0 @ M0^T + c0) * exp(-i t0) * (1 - exp(-i t0/2))  -> bufB [N,128]c
    cgemm_kernel<128,128,false,false,true><<<gemmGrid, 256, 0, stream>>>(
        bufA, M0r, M0i, c0r, c0i, t0r, t0i, (float2*)bufB, N);
    // bufA = h0 * exp(-i t0/2)   (accumulator init = h*ef; mix folded away)
    scale_kernel<<<(N * 128 + 255) / 256, 256, 0, stream>>>(
        (float2*)bufA, t0r, t0i, N * 128);
    // bufA += scatter of m0''   => bufA = x1
    {
        long long tot = (long long)E * 64;
        scatter_kernel<6><<<(unsigned)((tot + 255) / 256), 256, 0, stream>>>(
            (const float4*)bufB, src, dst, bufA, E, N);
    }

    // ---- layer 1 (packed into the two halves of bufB) ----
    float* h1 = bufB;                      // [N,64]c = N*128 floats
    float* m1 = bufB + (size_t)N * 128;    // [N,64]c = N*128 floats
    cgemm_kernel<128,64,false,true,false><<<gemmGrid, 256, 0, stream>>>(
        bufA, W1r, W1i, b1r, b1i, nullptr, nullptr, (float2*)h1, N);
    cgemm_kernel<64,64,false,false,true><<<gemmGrid, 256, 0, stream>>>(
        h1, M1r, M1i, c1r, c1i, t1r, t1i, (float2*)m1, N);
    scale_kernel<<<(N * 64 + 255) / 256, 256, 0, stream>>>(
        (float2*)h1, t1r, t1i, N * 64);
    {
        long long tot = (long long)E * 32;
        scatter_kernel<5><<<(unsigned)((tot + 255) / 256), 256, 0, stream>>>(
            (const float4*)m1, src, dst, h1, E, N);   // h1 becomes x2
    }

    // ---- readout ----
    hipMemsetAsync(sums, 0, (4096 + 64) * sizeof(float), stream);
    abs_reduce_kernel<<<(N * 64 + 255) / 256, 256, 0, stream>>>(
        (const float2*)h1, batch, sums, N);
    counts_kernel<<<(N + 255) / 256, 256, 0, stream>>>(batch, counts, N);
    finalize_kernel<<<64, 64, 0, stream>>>(sums, counts, (float*)d_out);
}

// Round 4
// 1904.210 us; speedup vs baseline: 5.0796x; 5.0796x over previous
//
#include <hip/hip_runtime.h>

// ---- bf16 helpers (stored as ushort) ----
__device__ __forceinline__ float b2f(unsigned short u) {
    return __uint_as_float(((unsigned int)u) << 16);
}
__device__ __forceinline__ unsigned short f2b(float f) {
    unsigned int u = __float_as_uint(f);
    unsigned int r = (u + 0x7FFFu + ((u >> 16) & 1u)) >> 16;   // RNE
    return (unsigned short)r;
}

// ---------------------------------------------------------------------------
// Complex GEMM: Out[n][j] = epilogue( sum_k X[n][k] * (Wr[j][k] + i*Wi[j][k]) + b[j] )
// XMODE: 0 = real fp32 [N,K], 1 = complex fp32 [N,K], 2 = complex bf16 [N,K]
// W: fp32 [J,K] row-major. Out: complex, fp32 (float2) or bf16 (packed uint).
// Epilogue: optional complex-relu; optional multiply by F = exp(-i t)*(1-exp(-i t/2)).
// ---------------------------------------------------------------------------
template<int K, int J, int XMODE, bool CRELU, bool TSCALE, bool OUTBF16>
__global__ __launch_bounds__(256) void cgemm_kernel(
    const void* __restrict__ Xv,
    const float* __restrict__ Wr,
    const float* __restrict__ Wi,
    const float* __restrict__ br,
    const float* __restrict__ bi,
    const float* __restrict__ trp,
    const float* __restrict__ tip,
    void* __restrict__ Outv, int nNodes)
{
    constexpr int TN   = 16;        // nodes per block
    constexpr int KC   = 32;        // K chunk
    constexpr int WROW = KC + 1;    // 33: bank = (j+kk)%32 -> conflict-free scalar reads
    constexpr int NG   = 256 / J;   // node groups
    constexpr int NPG  = TN / NG;   // nodes per thread
    static_assert(K % KC == 0, "K % KC");

    __shared__ float sWr[J * WROW];
    __shared__ float sWi[J * WROW];
    __shared__ float sX[TN * KC * (XMODE == 0 ? 1 : 2)];

    const int tid = threadIdx.x;
    const int j   = tid % J;
    const int g   = tid / J;
    const int n0  = blockIdx.x * TN;

    float accR[NPG], accI[NPG];
    #pragma unroll
    for (int i = 0; i < NPG; ++i) { accR[i] = 0.f; accI[i] = 0.f; }

    for (int kc = 0; kc < K; kc += KC) {
        // ---- stage W chunk ----
        {
            constexpr int TOT = J * (KC / 4);
            for (int idx = tid; idx < TOT; idx += 256) {
                int row = idx / (KC / 4);
                int col = (idx % (KC / 4)) * 4;
                float4 r  = *(const float4*)(Wr + (size_t)row * K + kc + col);
                float4 im = *(const float4*)(Wi + (size_t)row * K + kc + col);
                float* pr = sWr + row * WROW + col;
                float* pi = sWi + row * WROW + col;
                pr[0] = r.x;  pr[1] = r.y;  pr[2] = r.z;  pr[3] = r.w;
                pi[0] = im.x; pi[1] = im.y; pi[2] = im.z; pi[3] = im.w;
            }
        }
        // ---- stage X chunk (fp32 in LDS) ----
        if constexpr (XMODE == 0) {
            const float* X = (const float*)Xv;
            constexpr int TOT = TN * (KC / 4);
            for (int idx = tid; idx < TOT; idx += 256) {
                int row = idx / (KC / 4);
                int col = (idx % (KC / 4)) * 4;
                int n = n0 + row;
                float4 f = make_float4(0.f, 0.f, 0.f, 0.f);
                if (n < nNodes)
                    f = *(const float4*)(X + (size_t)n * K + kc + col);
                *(float4*)(sX + row * KC + col) = f;
            }
        } else if constexpr (XMODE == 1) {
            const float2* X = (const float2*)Xv;
            constexpr int TOT = TN * (KC / 2);
            for (int idx = tid; idx < TOT; idx += 256) {
                int row = idx / (KC / 2);
                int col = (idx % (KC / 2)) * 2;   // complex index
                int n = n0 + row;
                float4 f = make_float4(0.f, 0.f, 0.f, 0.f);
                if (n < nNodes)
                    f = *(const float4*)(X + (size_t)n * K + kc + col);
                *(float4*)(sX + (row * KC + col) * 2) = f;
            }
        } else {
            const unsigned short* X = (const unsigned short*)Xv;  // complex bf16, row = 2K ushorts
            constexpr int TOT = TN * (KC / 2);
            for (int idx = tid; idx < TOT; idx += 256) {
                int row = idx / (KC / 2);
                int col = (idx % (KC / 2)) * 2;   // complex index
                int n = n0 + row;
                float4 f = make_float4(0.f, 0.f, 0.f, 0.f);
                if (n < nNodes) {
                    ushort4 u = *(const ushort4*)(X + (size_t)n * 2 * K + (kc + col) * 2);
                    f = make_float4(b2f(u.x), b2f(u.y), b2f(u.z), b2f(u.w));
                }
                *(float4*)(sX + (row * KC + col) * 2) = f;
            }
        }
        __syncthreads();

        // ---- compute ----
        if constexpr (XMODE == 0) {
            #pragma unroll
            for (int kk = 0; kk < KC; kk += 4) {
                const float* wrp = sWr + j * WROW + kk;
                const float* wip = sWi + j * WROW + kk;
                float wr0 = wrp[0], wr1 = wrp[1], wr2 = wrp[2], wr3 = wrp[3];
                float wi0 = wip[0], wi1 = wip[1], wi2 = wip[2], wi3 = wip[3];
                #pragma unroll
                for (int nn = 0; nn < NPG; ++nn) {
                    int n = g * NPG + nn;
                    float4 x4 = *(const float4*)(sX + n * KC + kk);
                    accR[nn] += x4.x * wr0 + x4.y * wr1 + x4.z * wr2 + x4.w * wr3;
                    accI[nn] += x4.x * wi0 + x4.y * wi1 + x4.z * wi2 + x4.w * wi3;
                }
            }
        } else {
            #pragma unroll
            for (int kk = 0; kk < KC; kk += 2) {
                const float* wrp = sWr + j * WROW + kk;
                const float* wip = sWi + j * WROW + kk;
                float wr0 = wrp[0], wr1 = wrp[1];
                float wi0 = wip[0], wi1 = wip[1];
                #pragma unroll
                for (int nn = 0; nn < NPG; ++nn) {
                    int n = g * NPG + nn;
                    float4 x = *(const float4*)(sX + (n * KC + kk) * 2);  // 2 complex
                    accR[nn] += x.x * wr0 - x.y * wi0;
                    accI[nn] += x.x * wi0 + x.y * wr0;
                    accR[nn] += x.z * wr1 - x.w * wi1;
                    accI[nn] += x.z * wi1 + x.w * wr1;
                }
            }
        }
        __syncthreads();
    }

    // ---- epilogue ----
    float bre = br[j];
    float bim = bi[j];
    float Fr = 1.f, Fi = 0.f;
    if constexpr (TSCALE) {
        float tr = trp[0], ti = tip[0];
        float er  = expf(ti);                 // exp(-i t) = e^{ti}(cos tr - i sin tr)
        float tfr =  er * cosf(tr);
        float tfi = -er * sinf(tr);
        float eh  = expf(0.5f * ti);          // ef = exp(-i t/2)
        float efr =  eh * cosf(0.5f * tr);
        float efi = -eh * sinf(0.5f * tr);
        float omr = 1.f - efr, omi = -efi;    // (1 - ef)
        Fr = tfr * omr - tfi * omi;           // F = exp(-i t) * (1 - ef)
        Fi = tfr * omi + tfi * omr;
    }
    #pragma unroll
    for (int nn = 0; nn < NPG; ++nn) {
        int n = n0 + g * NPG + nn;
        if (n >= nNodes) continue;
        float a = accR[nn] + bre;
        float b = accI[nn] + bim;
        if constexpr (CRELU) { a = fmaxf(a, 0.f); b = fmaxf(b, 0.f); }
        if constexpr (TSCALE) {
            float na = a * Fr - b * Fi;
            float nb = a * Fi + b * Fr;
            a = na; b = nb;
        }
        if constexpr (OUTBF16) {
            unsigned int pk = (unsigned int)f2b(a) | ((unsigned int)f2b(b) << 16);
            ((unsigned int*)Outv)[(size_t)n * J + j] = pk;
        } else {
            ((float2*)Outv)[(size_t)n * J + j] = make_float2(a, b);
        }
    }
}

// ---------------------------------------------------------------------------
// CSR build: histogram -> exclusive scan -> placement (store src per slot)
// ---------------------------------------------------------------------------
__global__ __launch_bounds__(256) void hist_kernel(
    const int* __restrict__ src, const int* __restrict__ dst,
    int* __restrict__ deg, int E, int N)
{
    int e = blockIdx.x * 256 + threadIdx.x;
    if (e >= E) return;
    int s = src[e], d = dst[e];
    if ((unsigned)s >= (unsigned)N || (unsigned)d >= (unsigned)N) return;
    atomicAdd(&deg[d], 1);
}

__global__ __launch_bounds__(256) void scan1_kernel(
    const int* __restrict__ deg, int* __restrict__ row_off,
    int* __restrict__ partials, int N)
{
    __shared__ int sm[256];
    int i = blockIdx.x * 256 + threadIdx.x;
    int v = (i < N) ? deg[i] : 0;
    sm[threadIdx.x] = v;
    __syncthreads();
    #pragma unroll
    for (int o = 1; o < 256; o <<= 1) {
        int t = (threadIdx.x >= o) ? sm[threadIdx.x - o] : 0;
        __syncthreads();
        sm[threadIdx.x] += t;
        __syncthreads();
    }
    if (i < N) row_off[i] = sm[threadIdx.x] - v;   // exclusive within block
    if (threadIdx.x == 255) partials[blockIdx.x] = sm[255];
}

__global__ __launch_bounds__(512) void scan2_kernel(int* __restrict__ partials, int Nb)
{
    __shared__ int sm[512];
    int t = threadIdx.x;
    int v = (t < Nb) ? partials[t] : 0;
    sm[t] = v;
    __syncthreads();
    #pragma unroll
    for (int o = 1; o < 512; o <<= 1) {
        int x = (t >= o) ? sm[t - o] : 0;
        __syncthreads();
        sm[t] += x;
        __syncthreads();
    }
    if (t < Nb) partials[t] = sm[t] - v;   // exclusive
}

__global__ __launch_bounds__(256) void scan3_kernel(
    int* __restrict__ row_off, int* __restrict__ cursor,
    const int* __restrict__ partials, int N)
{
    int i = blockIdx.x * 256 + threadIdx.x;
    if (i >= N) return;
    int v = row_off[i] + partials[i >> 8];
    row_off[i] = v;
    cursor[i]  = v;
}

__global__ __launch_bounds__(256) void place_kernel(
    const int* __restrict__ src, const int* __restrict__ dst,
    int* __restrict__ cursor, int* __restrict__ csr_src, int E, int N)
{
    int e = blockIdx.x * 256 + threadIdx.x;
    if (e >= E) return;
    int s = src[e], d = dst[e];
    if ((unsigned)s >= (unsigned)N || (unsigned)d >= (unsigned)N) return;
    int pos = atomicAdd(&cursor[d], 1);
    csr_src[pos] = s;
}

// ---------------------------------------------------------------------------
// Layer-0 aggregate, in place: x[n] = ef*x[n] + sum_{e in CSR row n} msg[src_e]
// One wave per node; lane l holds float4 chunk l (2 complex). msg bf16 [N,256].
// ---------------------------------------------------------------------------
__global__ __launch_bounds__(256) void agg0_kernel(
    float* __restrict__ x, const unsigned short* __restrict__ msg,
    const int* __restrict__ row_off, const int* __restrict__ deg,
    const int* __restrict__ csr_src,
    const float* __restrict__ trp, const float* __restrict__ tip, int N)
{
    int wid  = (blockIdx.x * 256 + threadIdx.x) >> 6;
    int lane = threadIdx.x & 63;
    if (wid >= N) return;
    int start = row_off[wid];
    int cnt   = deg[wid];
    float4 acc = make_float4(0.f, 0.f, 0.f, 0.f);
    for (int e = 0; e < cnt; ++e) {
        int s = csr_src[start + e];
        ushort4 u = *(const ushort4*)(msg + ((size_t)s << 8) + (lane << 2));
        acc.x += b2f(u.x); acc.y += b2f(u.y); acc.z += b2f(u.z); acc.w += b2f(u.w);
    }
    float tr = trp[0], ti = tip[0];
    float eh  = expf(0.5f * ti);
    float efr =  eh * cosf(0.5f * tr);
    float efi = -eh * sinf(0.5f * tr);
    float* row = x + ((size_t)wid << 8) + (lane << 2);
    float4 h = *(const float4*)row;      // 2 complex: (x,y),(z,w)
    float4 o;
    o.x = h.x * efr - h.y * efi + acc.x;
    o.y = h.x * efi + h.y * efr + acc.y;
    o.z = h.z * efr - h.w * efi + acc.z;
    o.w = h.z * efi + h.w * efr + acc.w;
    *(float4*)row = o;
}

// ---------------------------------------------------------------------------
// Layer-1 aggregate + abs + per-graph sum. One wave per node; lane = feature.
// h1, msg: bf16 complex [N,64] (row = 128 ushorts). Never materializes x2.
// ---------------------------------------------------------------------------
__global__ __launch_bounds__(256) void agg1_kernel(
    const unsigned short* __restrict__ h1, const unsigned short* __restrict__ msg,
    const int* __restrict__ row_off, const int* __restrict__ deg,
    const int* __restrict__ csr_src,
    const float* __restrict__ trp, const float* __restrict__ tip,
    const int* __restrict__ batch, float* __restrict__ sums, int N)
{
    int wid  = (blockIdx.x * 256 + threadIdx.x) >> 6;
    int lane = threadIdx.x & 63;
    if (wid >= N) return;
    int start = row_off[wid];
    int cnt   = deg[wid];
    float ar = 0.f, ai = 0.f;
    for (int e = 0; e < cnt; ++e) {
        int s = csr_src[start + e];
        unsigned int u = *(const unsigned int*)(msg + ((size_t)s << 7) + (lane << 1));
        ar += b2f((unsigned short)(u & 0xffffu));
        ai += b2f((unsigned short)(u >> 16));
    }
    float tr = trp[0], ti = tip[0];
    float eh  = expf(0.5f * ti);
    float efr =  eh * cosf(0.5f * tr);
    float efi = -eh * sinf(0.5f * tr);
    unsigned int hu = *(const unsigned int*)(h1 + ((size_t)wid << 7) + (lane << 1));
    float hr = b2f((unsigned short)(hu & 0xffffu));
    float hi = b2f((unsigned short)(hu >> 16));
    float zr = hr * efr - hi * efi + ar;
    float zi = hr * efi + hi * efr + ai;
    float a = sqrtf(zr * zr + zi * zi);
    unsigned g = (unsigned)batch[wid];
    if (g < 64u) unsafeAtomicAdd(&sums[g * 64 + lane], a);
}

__global__ __launch_bounds__(256) void counts_kernel(
    const int* __restrict__ batch, float* __restrict__ counts, int nNodes)
{
    int n = blockIdx.x * 256 + threadIdx.x;
    if (n >= nNodes) return;
    unsigned g = (unsigned)batch[n];
    if (g < 64u) unsafeAtomicAdd(&counts[g], 1.0f);
}

// per-graph mean + log_softmax, one wave per graph
__global__ __launch_bounds__(64) void finalize_kernel(
    const float* __restrict__ sums, const float* __restrict__ counts,
    float* __restrict__ out)
{
    int g = blockIdx.x, d = threadIdx.x;
    float c = fmaxf(counts[g], 1.0f);
    float m = sums[g * 64 + d] / c;
    float mx = m;
    #pragma unroll
    for (int o = 32; o > 0; o >>= 1) mx = fmaxf(mx, __shfl_xor(mx, o, 64));
    float e = expf(m - mx);
    float s = e;
    #pragma unroll
    for (int o = 32; o > 0; o >>= 1) s += __shfl_xor(s, o, 64);
    out[g * 64 + d] = m - mx - logf(s);
}

extern "C" void kernel_launch(void* const* d_in, const int* in_sizes, int n_in,
                              void* d_out, int out_size, void* d_ws, size_t ws_size,
                              hipStream_t stream)
{
    const float* x   = (const float*)d_in[0];
    const float* W0r = (const float*)d_in[1];
    const float* W0i = (const float*)d_in[2];
    const float* b0r = (const float*)d_in[3];
    const float* b0i = (const float*)d_in[4];
    const float* M0r = (const float*)d_in[5];
    const float* M0i = (const float*)d_in[6];
    const float* c0r = (const float*)d_in[7];
    const float* c0i = (const float*)d_in[8];
    const float* t0r = (const float*)d_in[9];
    const float* t0i = (const float*)d_in[10];
    const float* W1r = (const float*)d_in[11];
    const float* W1i = (const float*)d_in[12];
    const float* b1r = (const float*)d_in[13];
    const float* b1i = (const float*)d_in[14];
    const float* M1r = (const float*)d_in[15];
    const float* M1i = (const float*)d_in[16];
    const float* c1r = (const float*)d_in[17];
    const float* c1i = (const float*)d_in[18];
    const float* t1r = (const float*)d_in[19];
    const float* t1i = (const float*)d_in[20];
    const int* edge  = (const int*)d_in[21];
    const int* batch = (const int*)d_in[22];

    const int N = in_sizes[0] / 128;
    const int E = in_sizes[21] / 2;
    const int* src = edge;
    const int* dst = edge + E;

    // ---- workspace layout ----
    // bufA fp32 [N,128]c (102.4MB) | msg bf16 [N,128]c (51.2MB) | h1 bf16 [N,64]c (25.6MB)
    // | deg,row_off,cursor (N ints each) | csr_src (E ints) | partials(512) | sums(4096) | counts(64)
    float*          bufA    = (float*)d_ws;
    unsigned short* msg     = (unsigned short*)(bufA + (size_t)N * 256);
    unsigned short* h1      = msg + (size_t)N * 256;
    int*            deg     = (int*)(h1 + (size_t)N * 128);
    int*            row_off = deg + N;
    int*            cursor  = row_off + N;
    int*            csr_src = cursor + N;
    int*            partial = csr_src + E;
    float*          sums    = (float*)(partial + 512);
    float*          counts  = sums + 4096;

    const int Nb = (N + 255) / 256;           // scan blocks (391 for N=100000)
    const int gemmGrid = (N + 15) / 16;
    const int edgeGrid = (E + 255) / 256;
    const int waveGrid = (N * 64 + 255) / 256; // one wave per node

    // ---- CSR build (reused by both layers) ----
    hipMemsetAsync(deg, 0, N * sizeof(int), stream);
    hist_kernel<<<edgeGrid, 256, 0, stream>>>(src, dst, deg, E, N);
    scan1_kernel<<<Nb, 256, 0, stream>>>(deg, row_off, partial, N);
    scan2_kernel<<<1, 512, 0, stream>>>(partial, Nb);
    scan3_kernel<<<Nb, 256, 0, stream>>>(row_off, cursor, partial, N);
    place_kernel<<<edgeGrid, 256, 0, stream>>>(src, dst, cursor, csr_src, E, N);

    // ---- layer 0 ----
    // h0 = crelu(x @ W0^T + b0) -> bufA fp32
    cgemm_kernel<128,128,0,true,false,false><<<gemmGrid, 256, 0, stream>>>(
        x, W0r, W0i, b0r, b0i, nullptr, nullptr, bufA, N);
    // m0'' = (h0 @ M0^T + c0) * exp(-i t0)(1-exp(-i t0/2)) -> msg bf16
    cgemm_kernel<128,128,1,false,true,true><<<gemmGrid, 256, 0, stream>>>(
        bufA, M0r, M0i, c0r, c0i, t0r, t0i, msg, N);
    // bufA = x1 = ef*h0 + csr-aggregate(msg)   (in place)
    agg0_kernel<<<waveGrid, 256, 0, stream>>>(
        bufA, msg, row_off, deg, csr_src, t0r, t0i, N);

    // ---- layer 1 ----
    // h1 = crelu(x1 @ W1^T + b1) -> bf16
    cgemm_kernel<128,64,1,true,false,true><<<gemmGrid, 256, 0, stream>>>(
        bufA, W1r, W1i, b1r, b1i, nullptr, nullptr, h1, N);
    // m1'' = (h1 @ M1^T + c1) * exp(-i t1)(1-exp(-i t1/2)) -> msg bf16 (first N*64c)
    cgemm_kernel<64,64,2,false,true,true><<<gemmGrid, 256, 0, stream>>>(
        h1, M1r, M1i, c1r, c1i, t1r, t1i, msg, N);

    // ---- fused layer-1 aggregate + abs + graph segment-sum ----
    hipMemsetAsync(sums, 0, (4096 + 64) * sizeof(float), stream);
    agg1_kernel<<<waveGrid, 256, 0, stream>>>(
        h1, msg, row_off, deg, csr_src, t1r, t1i, batch, sums, N);
    counts_kernel<<<(N + 255) / 256, 256, 0, stream>>>(batch, counts, N);
    finalize_kernel<<<64, 64, 0, stream>>>(sums, counts, (float*)d_out);
}

// Round 5
// 1360.880 us; speedup vs baseline: 7.1076x; 1.3992x over previous
//
#include <hip/hip_runtime.h>

// ---- bf16 helpers (stored as ushort) ----
__device__ __forceinline__ float b2f(unsigned short u) {
    return __uint_as_float(((unsigned int)u) << 16);
}
__device__ __forceinline__ unsigned short f2b(float f) {
    unsigned int u = __float_as_uint(f);
    unsigned int r = (u + 0x7FFFu + ((u >> 16) & 1u)) >> 16;   // RNE
    return (unsigned short)r;
}

// ---------------------------------------------------------------------------
// Complex GEMM: Out[n][j] = epilogue( sum_k X[n][k] * (Wr[j][k] + i*Wi[j][k]) + b[j] )
// XMODE: 0 = real fp32 [N,K], 1 = complex fp32 [N,K], 2 = complex bf16 [N,K]
// W: fp32 [J,K] row-major. Out: complex, fp32 (float2) or bf16 (packed uint).
// Epilogue: optional complex-relu; optional multiply by F = exp(-i t)*(1-exp(-i t/2)).
// ---------------------------------------------------------------------------
template<int K, int J, int XMODE, bool CRELU, bool TSCALE, bool OUTBF16>
__global__ __launch_bounds__(256) void cgemm_kernel(
    const void* __restrict__ Xv,
    const float* __restrict__ Wr,
    const float* __restrict__ Wi,
    const float* __restrict__ br,
    const float* __restrict__ bi,
    const float* __restrict__ trp,
    const float* __restrict__ tip,
    void* __restrict__ Outv, int nNodes)
{
    constexpr int TN   = 16;        // nodes per block
    constexpr int KC   = 32;        // K chunk
    constexpr int WROW = KC + 1;    // 33: bank = (j+kk)%32 -> conflict-free scalar reads
    constexpr int NG   = 256 / J;   // node groups
    constexpr int NPG  = TN / NG;   // nodes per thread
    static_assert(K % KC == 0, "K % KC");

    __shared__ float sWr[J * WROW];
    __shared__ float sWi[J * WROW];
    __shared__ float sX[TN * KC * (XMODE == 0 ? 1 : 2)];

    const int tid = threadIdx.x;
    const int j   = tid % J;
    const int g   = tid / J;
    const int n0  = blockIdx.x * TN;

    float accR[NPG], accI[NPG];
    #pragma unroll
    for (int i = 0; i < NPG; ++i) { accR[i] = 0.f; accI[i] = 0.f; }

    for (int kc = 0; kc < K; kc += KC) {
        // ---- stage W chunk ----
        {
            constexpr int TOT = J * (KC / 4);
            for (int idx = tid; idx < TOT; idx += 256) {
                int row = idx / (KC / 4);
                int col = (idx % (KC / 4)) * 4;
                float4 r  = *(const float4*)(Wr + (size_t)row * K + kc + col);
                float4 im = *(const float4*)(Wi + (size_t)row * K + kc + col);
                float* pr = sWr + row * WROW + col;
                float* pi = sWi + row * WROW + col;
                pr[0] = r.x;  pr[1] = r.y;  pr[2] = r.z;  pr[3] = r.w;
                pi[0] = im.x; pi[1] = im.y; pi[2] = im.z; pi[3] = im.w;
            }
        }
        // ---- stage X chunk (fp32 in LDS) ----
        if constexpr (XMODE == 0) {
            const float* X = (const float*)Xv;
            constexpr int TOT = TN * (KC / 4);
            for (int idx = tid; idx < TOT; idx += 256) {
                int row = idx / (KC / 4);
                int col = (idx % (KC / 4)) * 4;
                int n = n0 + row;
                float4 f = make_float4(0.f, 0.f, 0.f, 0.f);
                if (n < nNodes)
                    f = *(const float4*)(X + (size_t)n * K + kc + col);
                *(float4*)(sX + row * KC + col) = f;
            }
        } else if constexpr (XMODE == 1) {
            const float2* X = (const float2*)Xv;
            constexpr int TOT = TN * (KC / 2);
            for (int idx = tid; idx < TOT; idx += 256) {
                int row = idx / (KC / 2);
                int col = (idx % (KC / 2)) * 2;   // complex index
                int n = n0 + row;
                float4 f = make_float4(0.f, 0.f, 0.f, 0.f);
                if (n < nNodes)
                    f = *(const float4*)(X + (size_t)n * K + kc + col);
                *(float4*)(sX + (row * KC + col) * 2) = f;
            }
        } else {
            const unsigned short* X = (const unsigned short*)Xv;  // complex bf16, row = 2K ushorts
            constexpr int TOT = TN * (KC / 2);
            for (int idx = tid; idx < TOT; idx += 256) {
                int row = idx / (KC / 2);
                int col = (idx % (KC / 2)) * 2;   // complex index
                int n = n0 + row;
                float4 f = make_float4(0.f, 0.f, 0.f, 0.f);
                if (n < nNodes) {
                    ushort4 u = *(const ushort4*)(X + (size_t)n * 2 * K + (kc + col) * 2);
                    f = make_float4(b2f(u.x), b2f(u.y), b2f(u.z), b2f(u.w));
                }
                *(float4*)(sX + (row * KC + col) * 2) = f;
            }
        }
        __syncthreads();

        // ---- compute ----
        if constexpr (XMODE == 0) {
            #pragma unroll
            for (int kk = 0; kk < KC; kk += 4) {
                const float* wrp = sWr + j * WROW + kk;
                const float* wip = sWi + j * WROW + kk;
                float wr0 = wrp[0], wr1 = wrp[1], wr2 = wrp[2], wr3 = wrp[3];
                float wi0 = wip[0], wi1 = wip[1], wi2 = wip[2], wi3 = wip[3];
                #pragma unroll
                for (int nn = 0; nn < NPG; ++nn) {
                    int n = g * NPG + nn;
                    float4 x4 = *(const float4*)(sX + n * KC + kk);
                    accR[nn] += x4.x * wr0 + x4.y * wr1 + x4.z * wr2 + x4.w * wr3;
                    accI[nn] += x4.x * wi0 + x4.y * wi1 + x4.z * wi2 + x4.w * wi3;
                }
            }
        } else {
            #pragma unroll
            for (int kk = 0; kk < KC; kk += 2) {
                const float* wrp = sWr + j * WROW + kk;
                const float* wip = sWi + j * WROW + kk;
                float wr0 = wrp[0], wr1 = wrp[1];
                float wi0 = wip[0], wi1 = wip[1];
                #pragma unroll
                for (int nn = 0; nn < NPG; ++nn) {
                    int n = g * NPG + nn;
                    float4 x = *(const float4*)(sX + (n * KC + kk) * 2);  // 2 complex
                    accR[nn] += x.x * wr0 - x.y * wi0;
                    accI[nn] += x.x * wi0 + x.y * wr0;
                    accR[nn] += x.z * wr1 - x.w * wi1;
                    accI[nn] += x.z * wi1 + x.w * wr1;
                }
            }
        }
        __syncthreads();
    }

    // ---- epilogue ----
    float bre = br[j];
    float bim = bi[j];
    float Fr = 1.f, Fi = 0.f;
    if constexpr (TSCALE) {
        float tr = trp[0], ti = tip[0];
        float er  = expf(ti);                 // exp(-i t) = e^{ti}(cos tr - i sin tr)
        float tfr =  er * cosf(tr);
        float tfi = -er * sinf(tr);
        float eh  = expf(0.5f * ti);          // ef = exp(-i t/2)
        float efr =  eh * cosf(0.5f * tr);
        float efi = -eh * sinf(0.5f * tr);
        float omr = 1.f - efr, omi = -efi;    // (1 - ef)
        Fr = tfr * omr - tfi * omi;           // F = exp(-i t) * (1 - ef)
        Fi = tfr * omi + tfi * omr;
    }
    #pragma unroll
    for (int nn = 0; nn < NPG; ++nn) {
        int n = n0 + g * NPG + nn;
        if (n >= nNodes) continue;
        float a = accR[nn] + bre;
        float b = accI[nn] + bim;
        if constexpr (CRELU) { a = fmaxf(a, 0.f); b = fmaxf(b, 0.f); }
        if constexpr (TSCALE) {
            float na = a * Fr - b * Fi;
            float nb = a * Fi + b * Fr;
            a = na; b = nb;
        }
        if constexpr (OUTBF16) {
            unsigned int pk = (unsigned int)f2b(a) | ((unsigned int)f2b(b) << 16);
            ((unsigned int*)Outv)[(size_t)n * J + j] = pk;
        } else {
            ((float2*)Outv)[(size_t)n * J + j] = make_float2(a, b);
        }
    }
}

// ---------------------------------------------------------------------------
// CSR build: histogram -> exclusive scan -> placement (store src per slot)
// ---------------------------------------------------------------------------
__global__ __launch_bounds__(256) void hist_kernel(
    const int* __restrict__ src, const int* __restrict__ dst,
    int* __restrict__ deg, int E, int N)
{
    int e = blockIdx.x * 256 + threadIdx.x;
    if (e >= E) return;
    int s = src[e], d = dst[e];
    if ((unsigned)s >= (unsigned)N || (unsigned)d >= (unsigned)N) return;
    atomicAdd(&deg[d], 1);
}

__global__ __launch_bounds__(256) void scan1_kernel(
    const int* __restrict__ deg, int* __restrict__ row_off,
    int* __restrict__ partials, int N)
{
    __shared__ int sm[256];
    int i = blockIdx.x * 256 + threadIdx.x;
    int v = (i < N) ? deg[i] : 0;
    sm[threadIdx.x] = v;
    __syncthreads();
    #pragma unroll
    for (int o = 1; o < 256; o <<= 1) {
        int t = (threadIdx.x >= o) ? sm[threadIdx.x - o] : 0;
        __syncthreads();
        sm[threadIdx.x] += t;
        __syncthreads();
    }
    if (i < N) row_off[i] = sm[threadIdx.x] - v;   // exclusive within block
    if (threadIdx.x == 255) partials[blockIdx.x] = sm[255];
}

__global__ __launch_bounds__(512) void scan2_kernel(int* __restrict__ partials, int Nb)
{
    __shared__ int sm[512];
    int t = threadIdx.x;
    int v = (t < Nb) ? partials[t] : 0;
    sm[t] = v;
    __syncthreads();
    #pragma unroll
    for (int o = 1; o < 512; o <<= 1) {
        int x = (t >= o) ? sm[t - o] : 0;
        __syncthreads();
        sm[t] += x;
        __syncthreads();
    }
    if (t < Nb) partials[t] = sm[t] - v;   // exclusive
}

__global__ __launch_bounds__(256) void scan3_kernel(
    int* __restrict__ row_off, int* __restrict__ cursor,
    const int* __restrict__ partials, int N)
{
    int i = blockIdx.x * 256 + threadIdx.x;
    if (i >= N) return;
    int v = row_off[i] + partials[i >> 8];
    row_off[i] = v;
    cursor[i]  = v;
}

__global__ __launch_bounds__(256) void place_kernel(
    const int* __restrict__ src, const int* __restrict__ dst,
    int* __restrict__ cursor, int* __restrict__ csr_src, int E, int N)
{
    int e = blockIdx.x * 256 + threadIdx.x;
    if (e >= E) return;
    int s = src[e], d = dst[e];
    if ((unsigned)s >= (unsigned)N || (unsigned)d >= (unsigned)N) return;
    int pos = atomicAdd(&cursor[d], 1);
    csr_src[pos] = s;
}

// ---------------------------------------------------------------------------
// Layer-0 aggregate, in place: x[n] = ef*x[n] + sum_{e in CSR row n} msg[src_e]
// One wave per node; lane l holds float4 chunk l (2 complex). msg bf16 [N,256].
// ---------------------------------------------------------------------------
__global__ __launch_bounds__(256) void agg0_kernel(
    float* __restrict__ x, const unsigned short* __restrict__ msg,
    const int* __restrict__ row_off, const int* __restrict__ deg,
    const int* __restrict__ csr_src,
    const float* __restrict__ trp, const float* __restrict__ tip, int N)
{
    int wid  = (blockIdx.x * 256 + threadIdx.x) >> 6;
    int lane = threadIdx.x & 63;
    if (wid >= N) return;
    int start = row_off[wid];
    int cnt   = deg[wid];
    float4 acc = make_float4(0.f, 0.f, 0.f, 0.f);
    for (int e = 0; e < cnt; ++e) {
        int s = csr_src[start + e];
        ushort4 u = *(const ushort4*)(msg + ((size_t)s << 8) + (lane << 2));
        acc.x += b2f(u.x); acc.y += b2f(u.y); acc.z += b2f(u.z); acc.w += b2f(u.w);
    }
    float tr = trp[0], ti = tip[0];
    float eh  = expf(0.5f * ti);
    float efr =  eh * cosf(0.5f * tr);
    float efi = -eh * sinf(0.5f * tr);
    float* row = x + ((size_t)wid << 8) + (lane << 2);
    float4 h = *(const float4*)row;      // 2 complex: (x,y),(z,w)
    float4 o;
    o.x = h.x * efr - h.y * efi + acc.x;
    o.y = h.x * efi + h.y * efr + acc.y;
    o.z = h.z * efr - h.w * efi + acc.z;
    o.w = h.z * efi + h.w * efr + acc.w;
    *(float4*)row = o;
}

// ---------------------------------------------------------------------------
// Layer-1 aggregate + abs + per-graph sum. One wave per NPW consecutive nodes
// (batch sorted -> per-lane register accumulation, flush on graph change).
// h1, msg: bf16 complex [N,64] (row = 128 ushorts). Never materializes x2.
// ---------------------------------------------------------------------------
__global__ __launch_bounds__(256) void agg1_kernel(
    const unsigned short* __restrict__ h1, const unsigned short* __restrict__ msg,
    const int* __restrict__ row_off, const int* __restrict__ deg,
    const int* __restrict__ csr_src,
    const float* __restrict__ trp, const float* __restrict__ tip,
    const int* __restrict__ batch, float* __restrict__ sums, int N)
{
    constexpr int NPW = 16;   // nodes per wave
    int wid  = (blockIdx.x * 256 + threadIdx.x) >> 6;
    int lane = threadIdx.x & 63;
    int nBeg = wid * NPW;
    if (nBeg >= N) return;
    int nEnd = min(nBeg + NPW, N);

    float tr = trp[0], ti = tip[0];
    float eh  = expf(0.5f * ti);
    float efr =  eh * cosf(0.5f * tr);
    float efi = -eh * sinf(0.5f * tr);

    float acc = 0.f;
    int cur_g = batch[nBeg];

    for (int n = nBeg; n < nEnd; ++n) {
        int start = row_off[n];
        int cnt   = deg[n];
        float ar = 0.f, ai = 0.f;
        for (int e = 0; e < cnt; ++e) {
            int s = csr_src[start + e];
            unsigned int u = *(const unsigned int*)(msg + ((size_t)s << 7) + (lane << 1));
            ar += b2f((unsigned short)(u & 0xffffu));
            ai += b2f((unsigned short)(u >> 16));
        }
        unsigned int hu = *(const unsigned int*)(h1 + ((size_t)n << 7) + (lane << 1));
        float hr = b2f((unsigned short)(hu & 0xffffu));
        float hi = b2f((unsigned short)(hu >> 16));
        float zr = hr * efr - hi * efi + ar;
        float zi = hr * efi + hi * efr + ai;
        float a = sqrtf(zr * zr + zi * zi);
        int g = batch[n];                    // wave-uniform
        if (g != cur_g) {
            if ((unsigned)cur_g < 64u) unsafeAtomicAdd(&sums[cur_g * 64 + lane], acc);
            acc = 0.f;
            cur_g = g;
        }
        acc += a;
    }
    if ((unsigned)cur_g < 64u) unsafeAtomicAdd(&sums[cur_g * 64 + lane], acc);
}

// per-graph count via binary search (batch sorted) + mean + log_softmax.
// one block (64 threads) per graph.
__global__ __launch_bounds__(64) void finalize_kernel(
    const float* __restrict__ sums, const int* __restrict__ batch,
    float* __restrict__ out, int N)
{
    int g = blockIdx.x, d = threadIdx.x;
    __shared__ int cnt_s;
    if (d == 0) {
        // lower_bound(g) and lower_bound(g+1)
        int lo = 0, hi = N;
        while (lo < hi) { int mid = (lo + hi) >> 1; if (batch[mid] < g) lo = mid + 1; else hi = mid; }
        int lo2 = lo, hi2 = N;
        while (lo2 < hi2) { int mid = (lo2 + hi2) >> 1; if (batch[mid] < g + 1) lo2 = mid + 1; else hi2 = mid; }
        cnt_s = lo2 - lo;
    }
    __syncthreads();
    float c = fmaxf((float)cnt_s, 1.0f);
    float m = sums[g * 64 + d] / c;
    float mx = m;
    #pragma unroll
    for (int o = 32; o > 0; o >>= 1) mx = fmaxf(mx, __shfl_xor(mx, o, 64));
    float e = expf(m - mx);
    float s = e;
    #pragma unroll
    for (int o = 32; o > 0; o >>= 1) s += __shfl_xor(s, o, 64);
    out[g * 64 + d] = m - mx - logf(s);
}

extern "C" void kernel_launch(void* const* d_in, const int* in_sizes, int n_in,
                              void* d_out, int out_size, void* d_ws, size_t ws_size,
                              hipStream_t stream)
{
    const float* x   = (const float*)d_in[0];
    const float* W0r = (const float*)d_in[1];
    const float* W0i = (const float*)d_in[2];
    const float* b0r = (const float*)d_in[3];
    const float* b0i = (const float*)d_in[4];
    const float* M0r = (const float*)d_in[5];
    const float* M0i = (const float*)d_in[6];
    const float* c0r = (const float*)d_in[7];
    const float* c0i = (const float*)d_in[8];
    const float* t0r = (const float*)d_in[9];
    const float* t0i = (const float*)d_in[10];
    const float* W1r = (const float*)d_in[11];
    const float* W1i = (const float*)d_in[12];
    const float* b1r = (const float*)d_in[13];
    const float* b1i = (const float*)d_in[14];
    const float* M1r = (const float*)d_in[15];
    const float* M1i = (const float*)d_in[16];
    const float* c1r = (const float*)d_in[17];
    const float* c1i = (const float*)d_in[18];
    const float* t1r = (const float*)d_in[19];
    const float* t1i = (const float*)d_in[20];
    const int* edge  = (const int*)d_in[21];
    const int* batch = (const int*)d_in[22];

    const int N = in_sizes[0] / 128;
    const int E = in_sizes[21] / 2;
    const int* src = edge;
    const int* dst = edge + E;

    // ---- workspace layout ----
    // bufA fp32 [N,128]c (102.4MB) | msg bf16 [N,128]c (51.2MB) | h1 bf16 [N,64]c (25.6MB)
    // | deg,row_off,cursor (N ints each) | csr_src (E ints) | partials(512) | sums(4096)
    float*          bufA    = (float*)d_ws;
    unsigned short* msg     = (unsigned short*)(bufA + (size_t)N * 256);
    unsigned short* h1      = msg + (size_t)N * 256;
    int*            deg     = (int*)(h1 + (size_t)N * 128);
    int*            row_off = deg + N;
    int*            cursor  = row_off + N;
    int*            csr_src = cursor + N;
    int*            partial = csr_src + E;
    float*          sums    = (float*)(partial + 512);

    const int Nb = (N + 255) / 256;           // scan blocks
    const int gemmGrid = (N + 15) / 16;
    const int edgeGrid = (E + 255) / 256;
    const int waveGrid = (N * 64 + 255) / 256;       // one wave per node (agg0)
    const int wave16Grid = ((N + 15) / 16 * 64 + 255) / 256; // one wave per 16 nodes (agg1)

    // ---- CSR build (reused by both layers) ----
    hipMemsetAsync(deg, 0, N * sizeof(int), stream);
    hist_kernel<<<edgeGrid, 256, 0, stream>>>(src, dst, deg, E, N);
    scan1_kernel<<<Nb, 256, 0, stream>>>(deg, row_off, partial, N);
    scan2_kernel<<<1, 512, 0, stream>>>(partial, Nb);
    scan3_kernel<<<Nb, 256, 0, stream>>>(row_off, cursor, partial, N);
    place_kernel<<<edgeGrid, 256, 0, stream>>>(src, dst, cursor, csr_src, E, N);

    // ---- layer 0 ----
    // h0 = crelu(x @ W0^T + b0) -> bufA fp32
    cgemm_kernel<128,128,0,true,false,false><<<gemmGrid, 256, 0, stream>>>(
        x, W0r, W0i, b0r, b0i, nullptr, nullptr, bufA, N);
    // m0'' = (h0 @ M0^T + c0) * exp(-i t0)(1-exp(-i t0/2)) -> msg bf16
    cgemm_kernel<128,128,1,false,true,true><<<gemmGrid, 256, 0, stream>>>(
        bufA, M0r, M0i, c0r, c0i, t0r, t0i, msg, N);
    // bufA = x1 = ef*h0 + csr-aggregate(msg)   (in place)
    agg0_kernel<<<waveGrid, 256, 0, stream>>>(
        bufA, msg, row_off, deg, csr_src, t0r, t0i, N);

    // ---- layer 1 ----
    // h1 = crelu(x1 @ W1^T + b1) -> bf16
    cgemm_kernel<128,64,1,true,false,true><<<gemmGrid, 256, 0, stream>>>(
        bufA, W1r, W1i, b1r, b1i, nullptr, nullptr, h1, N);
    // m1'' = (h1 @ M1^T + c1) * exp(-i t1)(1-exp(-i t1/2)) -> msg bf16 (first N*64c)
    cgemm_kernel<64,64,2,false,true,true><<<gemmGrid, 256, 0, stream>>>(
        h1, M1r, M1i, c1r, c1i, t1r, t1i, msg, N);

    // ---- fused layer-1 aggregate + abs + graph segment-sum ----
    hipMemsetAsync(sums, 0, 4096 * sizeof(float), stream);
    agg1_kernel<<<wave16Grid, 256, 0, stream>>>(
        h1, msg, row_off, deg, csr_src, t1r, t1i, batch, sums, N);
    finalize_kernel<<<64, 64, 0, stream>>>(sums, batch, (float*)d_out, N);
}

// Round 6
// 892.899 us; speedup vs baseline: 10.8328x; 1.5241x over previous
//
#include <hip/hip_runtime.h>

typedef __attribute__((ext_vector_type(8))) short bf16x8;
typedef __attribute__((ext_vector_type(4))) float f32x4;

// ---- bf16 (as ushort) helpers ----
__device__ __forceinline__ float b2f(unsigned short u) {
    return __uint_as_float(((unsigned int)u) << 16);
}
__device__ __forceinline__ unsigned short f2b(float f) {
    unsigned int u = __float_as_uint(f);
    unsigned int r = (u + 0x7FFFu + ((u >> 16) & 1u)) >> 16;   // RNE
    return (unsigned short)r;
}

// ---------------------------------------------------------------------------
// MFMA complex GEMM as real GEMM:
//   D[f][n] = sum_c V[f][c] * A[n][c]
// A: node rows. REAL_IN ? fp32 [N,Kr] real : bf16 [N,Kr] complex-interleaved.
// V: [TWOJ, Kr] built in LDS from Wr/Wi fp32 [J,K]:
//   complex-in: V[2j]=[wr,-wi] interleaved, V[2j+1]=[wi,wr] interleaved
//   real-in:    V[2j]=wr row, V[2j+1]=wi row
// MFMA 16x16x32 bf16: a_frag = V rows (M=features), b_frag = node cols.
// D: row(feature) = q*4+reg, col(node) = lane&15  -> lane holds 4 consecutive
// interleaved features (2 complex) of one node -> 8B bf16 store.
// Epilogue: +bias, optional crelu, optional *F = exp(-i t)(1-exp(-i t/2)).
// Out: bf16 interleaved [N, TWOJ].
// ---------------------------------------------------------------------------
template<int Kr, int TWOJ, bool REAL_IN, bool CRELU, bool TSCALE>
__global__ __launch_bounds__(256) void mfma_cgemm_kernel(
    const void* __restrict__ Xv,
    const float* __restrict__ Wr, const float* __restrict__ Wi,
    const float* __restrict__ br, const float* __restrict__ bi,
    const float* __restrict__ trp, const float* __restrict__ tip,
    unsigned short* __restrict__ Out, int nNodes)
{
    constexpr int K      = REAL_IN ? Kr : Kr / 2;   // complex K of weight matrix
    constexpr int TILES  = TWOJ / 16;               // feature tiles per wave
    constexpr int CHUNKS = Kr / 32;
    constexpr int VROW   = 40;                      // ushort row stride (80 B, 16B-aligned)

    __shared__ __align__(16) unsigned short sV[TWOJ * VROW];
    __shared__ __align__(16) unsigned short sA[64 * VROW];

    const int tid  = threadIdx.x;
    const int w    = tid >> 6;        // wave id: nodes 16w..16w+15
    const int lane = tid & 63;
    const int l15  = lane & 15;
    const int q    = lane >> 4;
    const int n0   = blockIdx.x * 64;

    f32x4 acc[TILES];
    #pragma unroll
    for (int t = 0; t < TILES; ++t) acc[t] = (f32x4){0.f, 0.f, 0.f, 0.f};

    for (int kc = 0; kc < CHUNKS; ++kc) {
        // ---- stage V chunk: [TWOJ, 32] bf16 ----
        if constexpr (REAL_IN) {
            #pragma unroll
            for (int it = 0; it < TWOJ * 8 / 256; ++it) {
                int idx = it * 256 + tid;
                int f  = idx >> 3;
                int cg = idx & 7;                     // cols 4cg..4cg+3
                int j  = f >> 1;
                const float* wsrc = (f & 1) ? Wi : Wr;
                float4 v = *(const float4*)(wsrc + (size_t)j * K + kc * 32 + cg * 4);
                *(ushort4*)(sV + f * VROW + cg * 4) =
                    make_ushort4(f2b(v.x), f2b(v.y), f2b(v.z), f2b(v.w));
            }
        } else {
            #pragma unroll
            for (int it = 0; it < TWOJ * 8 / 256; ++it) {
                int idx = it * 256 + tid;
                int f  = idx >> 3;
                int cg = idx & 7;                     // complex k0 = kc*16 + 2cg, k0+1
                int j  = f >> 1;
                int k0 = kc * 16 + cg * 2;
                float2 wr2 = *(const float2*)(Wr + (size_t)j * K + k0);
                float2 wi2 = *(const float2*)(Wi + (size_t)j * K + k0);
                ushort4 u;
                if (f & 1) u = make_ushort4(f2b(wi2.x), f2b(wr2.x), f2b(wi2.y), f2b(wr2.y));
                else       u = make_ushort4(f2b(wr2.x), f2b(-wi2.x), f2b(wr2.y), f2b(-wi2.y));
                *(ushort4*)(sV + f * VROW + cg * 4) = u;
            }
        }
        // ---- stage A chunk: [64, 32] bf16 ----
        if constexpr (REAL_IN) {
            const float* X = (const float*)Xv;
            #pragma unroll
            for (int it = 0; it < 2; ++it) {
                int idx = it * 256 + tid;
                int nl = idx >> 3;
                int cg = idx & 7;
                int n  = n0 + nl;
                float4 v = make_float4(0.f, 0.f, 0.f, 0.f);
                if (n < nNodes)
                    v = *(const float4*)(X + (size_t)n * Kr + kc * 32 + cg * 4);
                *(ushort4*)(sA + nl * VROW + cg * 4) =
                    make_ushort4(f2b(v.x), f2b(v.y), f2b(v.z), f2b(v.w));
            }
        } else {
            const unsigned short* X = (const unsigned short*)Xv;
            int nl = tid >> 2;
            int cg = tid & 3;                         // 8 cols per thread
            int n  = n0 + nl;
            ushort4 a = make_ushort4(0,0,0,0), b = make_ushort4(0,0,0,0);
            if (n < nNodes) {
                const unsigned short* p = X + (size_t)n * Kr + kc * 32 + cg * 8;
                a = *(const ushort4*)(p);
                b = *(const ushort4*)(p + 4);
            }
            *(ushort4*)(sA + nl * VROW + cg * 8)     = a;
            *(ushort4*)(sA + nl * VROW + cg * 8 + 4) = b;
        }
        __syncthreads();

        // ---- mfma: b_frag = wave's 16 nodes (reused across all feature tiles) ----
        bf16x8 bfrag = *(const bf16x8*)(sA + (w * 16 + l15) * VROW + q * 8);
        const unsigned short* vbase = sV + l15 * VROW + q * 8;
        #pragma unroll
        for (int t = 0; t < TILES; ++t) {
            bf16x8 afrag = *(const bf16x8*)(vbase + t * 16 * VROW);
            acc[t] = __builtin_amdgcn_mfma_f32_16x16x32_bf16(afrag, bfrag, acc[t], 0, 0, 0);
        }
        __syncthreads();
    }

    // ---- epilogue ----
    int n = n0 + w * 16 + l15;
    if (n >= nNodes) return;
    float Fr = 1.f, Fi = 0.f;
    if constexpr (TSCALE) {
        float tr = trp[0], ti = tip[0];
        float er  = expf(ti);                  // exp(-i t) = e^{ti}(cos tr - i sin tr)
        float tfr =  er * cosf(tr);
        float tfi = -er * sinf(tr);
        float eh  = expf(0.5f * ti);           // ef = exp(-i t/2)
        float efr =  eh * cosf(0.5f * tr);
        float efi = -eh * sinf(0.5f * tr);
        float omr = 1.f - efr, omi = -efi;     // (1 - ef)
        Fr = tfr * omr - tfi * omi;            // F = exp(-i t)(1 - ef)
        Fi = tfr * omi + tfi * omr;
    }
    #pragma unroll
    for (int t = 0; t < TILES; ++t) {
        int f0 = t * 16 + q * 4;               // even -> complex j0, j0+1
        int j0 = f0 >> 1;
        float re0 = acc[t][0] + br[j0];
        float im0 = acc[t][1] + bi[j0];
        float re1 = acc[t][2] + br[j0 + 1];
        float im1 = acc[t][3] + bi[j0 + 1];
        if constexpr (CRELU) {
            re0 = fmaxf(re0, 0.f); im0 = fmaxf(im0, 0.f);
            re1 = fmaxf(re1, 0.f); im1 = fmaxf(im1, 0.f);
        }
        if constexpr (TSCALE) {
            float r0 = re0 * Fr - im0 * Fi, i0 = re0 * Fi + im0 * Fr;
            float r1 = re1 * Fr - im1 * Fi, i1 = re1 * Fi + im1 * Fr;
            re0 = r0; im0 = i0; re1 = r1; im1 = i1;
        }
        *(ushort4*)(Out + (size_t)n * TWOJ + f0) =
            make_ushort4(f2b(re0), f2b(im0), f2b(re1), f2b(im1));
    }
}

// ---------------------------------------------------------------------------
// CSR build: histogram -> exclusive scan -> placement
// ---------------------------------------------------------------------------
__global__ __launch_bounds__(256) void hist_kernel(
    const int* __restrict__ src, const int* __restrict__ dst,
    int* __restrict__ deg, int E, int N)
{
    int e = blockIdx.x * 256 + threadIdx.x;
    if (e >= E) return;
    int s = src[e], d = dst[e];
    if ((unsigned)s >= (unsigned)N || (unsigned)d >= (unsigned)N) return;
    atomicAdd(&deg[d], 1);
}

__global__ __launch_bounds__(256) void scan1_kernel(
    const int* __restrict__ deg, int* __restrict__ row_off,
    int* __restrict__ partials, int N)
{
    __shared__ int sm[256];
    int i = blockIdx.x * 256 + threadIdx.x;
    int v = (i < N) ? deg[i] : 0;
    sm[threadIdx.x] = v;
    __syncthreads();
    #pragma unroll
    for (int o = 1; o < 256; o <<= 1) {
        int t = (threadIdx.x >= o) ? sm[threadIdx.x - o] : 0;
        __syncthreads();
        sm[threadIdx.x] += t;
        __syncthreads();
    }
    if (i < N) row_off[i] = sm[threadIdx.x] - v;
    if (threadIdx.x == 255) partials[blockIdx.x] = sm[255];
}

__global__ __launch_bounds__(512) void scan2_kernel(int* __restrict__ partials, int Nb)
{
    __shared__ int sm[512];
    int t = threadIdx.x;
    int v = (t < Nb) ? partials[t] : 0;
    sm[t] = v;
    __syncthreads();
    #pragma unroll
    for (int o = 1; o < 512; o <<= 1) {
        int x = (t >= o) ? sm[t - o] : 0;
        __syncthreads();
        sm[t] += x;
        __syncthreads();
    }
    if (t < Nb) partials[t] = sm[t] - v;
}

__global__ __launch_bounds__(256) void scan3_kernel(
    int* __restrict__ row_off, int* __restrict__ cursor,
    const int* __restrict__ partials, int N)
{
    int i = blockIdx.x * 256 + threadIdx.x;
    if (i >= N) return;
    int v = row_off[i] + partials[i >> 8];
    row_off[i] = v;
    cursor[i]  = v;
}

__global__ __launch_bounds__(256) void place_kernel(
    const int* __restrict__ src, const int* __restrict__ dst,
    int* __restrict__ cursor, int* __restrict__ csr_src, int E, int N)
{
    int e = blockIdx.x * 256 + threadIdx.x;
    if (e >= E) return;
    int s = src[e], d = dst[e];
    if ((unsigned)s >= (unsigned)N || (unsigned)d >= (unsigned)N) return;
    int pos = atomicAdd(&cursor[d], 1);
    csr_src[pos] = s;
}

// ---------------------------------------------------------------------------
// Layer-0 aggregate, in place (bf16): h[n] = ef*h[n] + sum msg[src]
// One wave per node; lane holds 4 bf16 (2 complex). Rows = 256 ushorts.
// ---------------------------------------------------------------------------
__global__ __launch_bounds__(256) void agg0_kernel(
    unsigned short* __restrict__ h, const unsigned short* __restrict__ msg,
    const int* __restrict__ row_off, const int* __restrict__ deg,
    const int* __restrict__ csr_src,
    const float* __restrict__ trp, const float* __restrict__ tip, int N)
{
    int wid  = (blockIdx.x * 256 + threadIdx.x) >> 6;
    int lane = threadIdx.x & 63;
    if (wid >= N) return;
    int start = row_off[wid];
    int cnt   = deg[wid];
    float a0 = 0.f, a1 = 0.f, a2 = 0.f, a3 = 0.f;
    for (int e = 0; e < cnt; ++e) {
        int s = csr_src[start + e];
        ushort4 u = *(const ushort4*)(msg + ((size_t)s << 8) + (lane << 2));
        a0 += b2f(u.x); a1 += b2f(u.y); a2 += b2f(u.z); a3 += b2f(u.w);
    }
    float tr = trp[0], ti = tip[0];
    float eh  = expf(0.5f * ti);
    float efr =  eh * cosf(0.5f * tr);
    float efi = -eh * sinf(0.5f * tr);
    unsigned short* row = h + ((size_t)wid << 8) + (lane << 2);
    ushort4 hu = *(const ushort4*)row;
    float hr0 = b2f(hu.x), hi0 = b2f(hu.y), hr1 = b2f(hu.z), hi1 = b2f(hu.w);
    float o0 = hr0 * efr - hi0 * efi + a0;
    float o1 = hr0 * efi + hi0 * efr + a1;
    float o2 = hr1 * efr - hi1 * efi + a2;
    float o3 = hr1 * efi + hi1 * efr + a3;
    *(ushort4*)row = make_ushort4(f2b(o0), f2b(o1), f2b(o2), f2b(o3));
}

// ---------------------------------------------------------------------------
// Layer-1 aggregate + abs + per-graph sum. One wave per 16 consecutive nodes
// (batch sorted -> per-lane register accumulation, flush on graph change).
// h1, msg: bf16 complex [N,64] (row = 128 ushorts).
// ---------------------------------------------------------------------------
__global__ __launch_bounds__(256) void agg1_kernel(
    const unsigned short* __restrict__ h1, const unsigned short* __restrict__ msg,
    const int* __restrict__ row_off, const int* __restrict__ deg,
    const int* __restrict__ csr_src,
    const float* __restrict__ trp, const float* __restrict__ tip,
    const int* __restrict__ batch, float* __restrict__ sums, int N)
{
    constexpr int NPW = 16;
    int wid  = (blockIdx.x * 256 + threadIdx.x) >> 6;
    int lane = threadIdx.x & 63;
    int nBeg = wid * NPW;
    if (nBeg >= N) return;
    int nEnd = min(nBeg + NPW, N);

    float tr = trp[0], ti = tip[0];
    float eh  = expf(0.5f * ti);
    float efr =  eh * cosf(0.5f * tr);
    float efi = -eh * sinf(0.5f * tr);

    float acc = 0.f;
    int cur_g = batch[nBeg];

    for (int n = nBeg; n < nEnd; ++n) {
        int start = row_off[n];
        int cnt   = deg[n];
        float ar = 0.f, ai = 0.f;
        for (int e = 0; e < cnt; ++e) {
            int s = csr_src[start + e];
            unsigned int u = *(const unsigned int*)(msg + ((size_t)s << 7) + (lane << 1));
            ar += b2f((unsigned short)(u & 0xffffu));
            ai += b2f((unsigned short)(u >> 16));
        }
        unsigned int hu = *(const unsigned int*)(h1 + ((size_t)n << 7) + (lane << 1));
        float hr = b2f((unsigned short)(hu & 0xffffu));
        float hi = b2f((unsigned short)(hu >> 16));
        float zr = hr * efr - hi * efi + ar;
        float zi = hr * efi + hi * efr + ai;
        float a = sqrtf(zr * zr + zi * zi);
        int g = batch[n];
        if (g != cur_g) {
            if ((unsigned)cur_g < 64u) unsafeAtomicAdd(&sums[cur_g * 64 + lane], acc);
            acc = 0.f;
            cur_g = g;
        }
        acc += a;
    }
    if ((unsigned)cur_g < 64u) unsafeAtomicAdd(&sums[cur_g * 64 + lane], acc);
}

// per-graph count via binary search (batch sorted) + mean + log_softmax
__global__ __launch_bounds__(64) void finalize_kernel(
    const float* __restrict__ sums, const int* __restrict__ batch,
    float* __restrict__ out, int N)
{
    int g = blockIdx.x, d = threadIdx.x;
    __shared__ int cnt_s;
    if (d == 0) {
        int lo = 0, hi = N;
        while (lo < hi) { int mid = (lo + hi) >> 1; if (batch[mid] < g) lo = mid + 1; else hi = mid; }
        int lo2 = lo, hi2 = N;
        while (lo2 < hi2) { int mid = (lo2 + hi2) >> 1; if (batch[mid] < g + 1) lo2 = mid + 1; else hi2 = mid; }
        cnt_s = lo2 - lo;
    }
    __syncthreads();
    float c = fmaxf((float)cnt_s, 1.0f);
    float m = sums[g * 64 + d] / c;
    float mx = m;
    #pragma unroll
    for (int o = 32; o > 0; o >>= 1) mx = fmaxf(mx, __shfl_xor(mx, o, 64));
    float e = expf(m - mx);
    float s = e;
    #pragma unroll
    for (int o = 32; o > 0; o >>= 1) s += __shfl_xor(s, o, 64);
    out[g * 64 + d] = m - mx - logf(s);
}

extern "C" void kernel_launch(void* const* d_in, const int* in_sizes, int n_in,
                              void* d_out, int out_size, void* d_ws, size_t ws_size,
                              hipStream_t stream)
{
    const float* x   = (const float*)d_in[0];
    const float* W0r = (const float*)d_in[1];
    const float* W0i = (const float*)d_in[2];
    const float* b0r = (const float*)d_in[3];
    const float* b0i = (const float*)d_in[4];
    const float* M0r = (const float*)d_in[5];
    const float* M0i = (const float*)d_in[6];
    const float* c0r = (const float*)d_in[7];
    const float* c0i = (const float*)d_in[8];
    const float* t0r = (const float*)d_in[9];
    const float* t0i = (const float*)d_in[10];
    const float* W1r = (const float*)d_in[11];
    const float* W1i = (const float*)d_in[12];
    const float* b1r = (const float*)d_in[13];
    const float* b1i = (const float*)d_in[14];
    const float* M1r = (const float*)d_in[15];
    const float* M1i = (const float*)d_in[16];
    const float* c1r = (const float*)d_in[17];
    const float* c1i = (const float*)d_in[18];
    const float* t1r = (const float*)d_in[19];
    const float* t1i = (const float*)d_in[20];
    const int* edge  = (const int*)d_in[21];
    const int* batch = (const int*)d_in[22];

    const int N = in_sizes[0] / 128;
    const int E = in_sizes[21] / 2;
    const int* src = edge;
    const int* dst = edge + E;

    // ---- workspace (all bf16 activations): ~161 MB ----
    // bufH [N,256] (h0 -> x1 in place) | msg0 [N,256] | h1 [N,128] | m1 [N,128]
    // | deg,row_off,cursor (N ints) | csr_src (E ints) | partial(512) | sums(4096 f32)
    unsigned short* bufH = (unsigned short*)d_ws;
    unsigned short* msg0 = bufH + (size_t)N * 256;
    unsigned short* h1   = msg0 + (size_t)N * 256;
    unsigned short* m1   = h1 + (size_t)N * 128;
    int*   deg     = (int*)(m1 + (size_t)N * 128);
    int*   row_off = deg + N;
    int*   cursor  = row_off + N;
    int*   csr_src = cursor + N;
    int*   partial = csr_src + E;
    float* sums    = (float*)(partial + 512);

    const int Nb = (N + 255) / 256;
    const int gemmGrid = (N + 63) / 64;
    const int edgeGrid = (E + 255) / 256;
    const int waveGrid = (N * 64 + 255) / 256;                 // wave/node (agg0)
    const int wave16Grid = ((N + 15) / 16 * 64 + 255) / 256;   // wave/16 nodes (agg1)

    // ---- CSR build ----
    hipMemsetAsync(deg, 0, N * sizeof(int), stream);
    hist_kernel<<<edgeGrid, 256, 0, stream>>>(src, dst, deg, E, N);
    scan1_kernel<<<Nb, 256, 0, stream>>>(deg, row_off, partial, N);
    scan2_kernel<<<1, 512, 0, stream>>>(partial, Nb);
    scan3_kernel<<<Nb, 256, 0, stream>>>(row_off, cursor, partial, N);
    place_kernel<<<edgeGrid, 256, 0, stream>>>(src, dst, cursor, csr_src, E, N);

    // ---- layer 0 ----
    // h0 = crelu(x @ W0^T + b0) -> bufH bf16 [N,256]
    mfma_cgemm_kernel<128,256,true,true,false><<<gemmGrid, 256, 0, stream>>>(
        x, W0r, W0i, b0r, b0i, nullptr, nullptr, bufH, N);
    // m0'' = (h0 @ M0^T + c0) * F0 -> msg0 bf16 [N,256]
    mfma_cgemm_kernel<256,256,false,false,true><<<gemmGrid, 256, 0, stream>>>(
        bufH, M0r, M0i, c0r, c0i, t0r, t0i, msg0, N);
    // bufH = x1 = ef*h0 + csr-aggregate(msg0)   (in place)
    agg0_kernel<<<waveGrid, 256, 0, stream>>>(
        bufH, msg0, row_off, deg, csr_src, t0r, t0i, N);

    // ---- layer 1 ----
    // h1 = crelu(x1 @ W1^T + b1) -> bf16 [N,128]
    mfma_cgemm_kernel<256,128,false,true,false><<<gemmGrid, 256, 0, stream>>>(
        bufH, W1r, W1i, b1r, b1i, nullptr, nullptr, h1, N);
    // m1'' = (h1 @ M1^T + c1) * F1 -> bf16 [N,128]
    mfma_cgemm_kernel<128,128,false,false,true><<<gemmGrid, 256, 0, stream>>>(
        h1, M1r, M1i, c1r, c1i, t1r, t1i, m1, N);

    // ---- fused layer-1 aggregate + abs + graph segment-sum ----
    hipMemsetAsync(sums, 0, 4096 * sizeof(float), stream);
    agg1_kernel<<<wave16Grid, 256, 0, stream>>>(
        h1, m1, row_off, deg, csr_src, t1r, t1i, batch, sums, N);
    finalize_kernel<<<64, 64, 0, stream>>>(sums, batch, (float*)d_out, N);
}

// Round 7
// 729.013 us; speedup vs baseline: 13.2681x; 1.2248x over previous
//
#include <hip/hip_runtime.h>

typedef __attribute__((ext_vector_type(8))) short bf16x8;
typedef __attribute__((ext_vector_type(4))) float f32x4;

// ---- bf16 (as ushort) helpers ----
__device__ __forceinline__ float b2f(unsigned short u) {
    return __uint_as_float(((unsigned int)u) << 16);
}
__device__ __forceinline__ unsigned short f2b(float f) {
    unsigned int u = __float_as_uint(f);
    unsigned int r = (u + 0x7FFFu + ((u >> 16) & 1u)) >> 16;   // RNE
    return (unsigned short)r;
}

// ---------------------------------------------------------------------------
// MFMA complex GEMM as real GEMM:  D[f][n] = sum_c V[f][c] * A[n][c]
// A: node rows. REAL_IN ? fp32 [N,Kr] real : bf16 [N,Kr] complex-interleaved.
// V: [TWOJ, Kr] built in LDS from Wr/Wi fp32 [J,K]:
//   complex-in: V[2j]=[wr,-wi] interleaved, V[2j+1]=[wi,wr] interleaved
//   real-in:    V[2j]=wr row, V[2j+1]=wi row
// Epilogues:
//   MIX=false: +bias(br,bi), optional CRELU                  (W-layers)
//   MIX=true : out = ef*Hin[n] + F*(acc + deg[n]*c), where   (M-layers)
//              F = exp(-i t)*(1 - exp(-i t/2)), ef = exp(-i t/2);
//              br/bi act as cr/ci.
// Out: bf16 interleaved [N, TWOJ].
// ---------------------------------------------------------------------------
template<int Kr, int TWOJ, bool REAL_IN, bool CRELU, bool MIX>
__global__ __launch_bounds__(256) void mfma_cgemm_kernel(
    const void* __restrict__ Xv,
    const float* __restrict__ Wr, const float* __restrict__ Wi,
    const float* __restrict__ br, const float* __restrict__ bi,
    const float* __restrict__ trp, const float* __restrict__ tip,
    const unsigned short* __restrict__ Hin, const int* __restrict__ degp,
    unsigned short* __restrict__ Out, int nNodes)
{
    constexpr int K      = REAL_IN ? Kr : Kr / 2;   // complex K of weight matrix
    constexpr int TILES  = TWOJ / 16;
    constexpr int CHUNKS = Kr / 32;
    constexpr int VROW   = 40;                      // ushort row stride (80 B)

    __shared__ __align__(16) unsigned short sV[TWOJ * VROW];
    __shared__ __align__(16) unsigned short sA[64 * VROW];

    const int tid  = threadIdx.x;
    const int w    = tid >> 6;
    const int lane = tid & 63;
    const int l15  = lane & 15;
    const int q    = lane >> 4;
    const int n0   = blockIdx.x * 64;

    f32x4 acc[TILES];
    #pragma unroll
    for (int t = 0; t < TILES; ++t) acc[t] = (f32x4){0.f, 0.f, 0.f, 0.f};

    for (int kc = 0; kc < CHUNKS; ++kc) {
        // ---- stage V chunk: [TWOJ, 32] bf16 ----
        if constexpr (REAL_IN) {
            #pragma unroll
            for (int it = 0; it < TWOJ * 8 / 256; ++it) {
                int idx = it * 256 + tid;
                int f  = idx >> 3;
                int cg = idx & 7;
                int j  = f >> 1;
                const float* wsrc = (f & 1) ? Wi : Wr;
                float4 v = *(const float4*)(wsrc + (size_t)j * K + kc * 32 + cg * 4);
                *(ushort4*)(sV + f * VROW + cg * 4) =
                    make_ushort4(f2b(v.x), f2b(v.y), f2b(v.z), f2b(v.w));
            }
        } else {
            #pragma unroll
            for (int it = 0; it < TWOJ * 8 / 256; ++it) {
                int idx = it * 256 + tid;
                int f  = idx >> 3;
                int cg = idx & 7;
                int j  = f >> 1;
                int k0 = kc * 16 + cg * 2;
                float2 wr2 = *(const float2*)(Wr + (size_t)j * K + k0);
                float2 wi2 = *(const float2*)(Wi + (size_t)j * K + k0);
                ushort4 u;
                if (f & 1) u = make_ushort4(f2b(wi2.x), f2b(wr2.x), f2b(wi2.y), f2b(wr2.y));
                else       u = make_ushort4(f2b(wr2.x), f2b(-wi2.x), f2b(wr2.y), f2b(-wi2.y));
                *(ushort4*)(sV + f * VROW + cg * 4) = u;
            }
        }
        // ---- stage A chunk: [64, 32] bf16 ----
        if constexpr (REAL_IN) {
            const float* X = (const float*)Xv;
            #pragma unroll
            for (int it = 0; it < 2; ++it) {
                int idx = it * 256 + tid;
                int nl = idx >> 3;
                int cg = idx & 7;
                int n  = n0 + nl;
                float4 v = make_float4(0.f, 0.f, 0.f, 0.f);
                if (n < nNodes)
                    v = *(const float4*)(X + (size_t)n * Kr + kc * 32 + cg * 4);
                *(ushort4*)(sA + nl * VROW + cg * 4) =
                    make_ushort4(f2b(v.x), f2b(v.y), f2b(v.z), f2b(v.w));
            }
        } else {
            const unsigned short* X = (const unsigned short*)Xv;
            int nl = tid >> 2;
            int cg = tid & 3;
            int n  = n0 + nl;
            ushort4 a = make_ushort4(0,0,0,0), b = make_ushort4(0,0,0,0);
            if (n < nNodes) {
                const unsigned short* p = X + (size_t)n * Kr + kc * 32 + cg * 8;
                a = *(const ushort4*)(p);
                b = *(const ushort4*)(p + 4);
            }
            *(ushort4*)(sA + nl * VROW + cg * 8)     = a;
            *(ushort4*)(sA + nl * VROW + cg * 8 + 4) = b;
        }
        __syncthreads();

        bf16x8 bfrag = *(const bf16x8*)(sA + (w * 16 + l15) * VROW + q * 8);
        const unsigned short* vbase = sV + l15 * VROW + q * 8;
        #pragma unroll
        for (int t = 0; t < TILES; ++t) {
            bf16x8 afrag = *(const bf16x8*)(vbase + t * 16 * VROW);
            acc[t] = __builtin_amdgcn_mfma_f32_16x16x32_bf16(afrag, bfrag, acc[t], 0, 0, 0);
        }
        __syncthreads();
    }

    // ---- epilogue ----
    int n = n0 + w * 16 + l15;
    if (n >= nNodes) return;
    float Fr = 1.f, Fi = 0.f, efr = 1.f, efi = 0.f, dg = 0.f;
    if constexpr (MIX) {
        float tr = trp[0], ti = tip[0];
        float er  = expf(ti);                  // exp(-i t) = e^{ti}(cos tr - i sin tr)
        float tfr =  er * cosf(tr);
        float tfi = -er * sinf(tr);
        float eh  = expf(0.5f * ti);           // ef = exp(-i t/2)
        efr =  eh * cosf(0.5f * tr);
        efi = -eh * sinf(0.5f * tr);
        float omr = 1.f - efr, omi = -efi;     // (1 - ef)
        Fr = tfr * omr - tfi * omi;            // F = exp(-i t)(1 - ef)
        Fi = tfr * omi + tfi * omr;
        dg = (float)degp[n];
    }
    #pragma unroll
    for (int t = 0; t < TILES; ++t) {
        int f0 = t * 16 + q * 4;
        int j0 = f0 >> 1;
        float re0, im0, re1, im1;
        if constexpr (MIX) {
            // acc + deg*c, then *F, then + ef*Hin
            float ar0 = acc[t][0] + dg * br[j0];
            float ai0 = acc[t][1] + dg * bi[j0];
            float ar1 = acc[t][2] + dg * br[j0 + 1];
            float ai1 = acc[t][3] + dg * bi[j0 + 1];
            re0 = ar0 * Fr - ai0 * Fi;  im0 = ar0 * Fi + ai0 * Fr;
            re1 = ar1 * Fr - ai1 * Fi;  im1 = ar1 * Fi + ai1 * Fr;
            ushort4 hu = *(const ushort4*)(Hin + (size_t)n * TWOJ + f0);
            float hr0 = b2f(hu.x), hi0 = b2f(hu.y), hr1 = b2f(hu.z), hi1 = b2f(hu.w);
            re0 += hr0 * efr - hi0 * efi;  im0 += hr0 * efi + hi0 * efr;
            re1 += hr1 * efr - hi1 * efi;  im1 += hr1 * efi + hi1 * efr;
        } else {
            re0 = acc[t][0] + br[j0];
            im0 = acc[t][1] + bi[j0];
            re1 = acc[t][2] + br[j0 + 1];
            im1 = acc[t][3] + bi[j0 + 1];
            if constexpr (CRELU) {
                re0 = fmaxf(re0, 0.f); im0 = fmaxf(im0, 0.f);
                re1 = fmaxf(re1, 0.f); im1 = fmaxf(im1, 0.f);
            }
        }
        *(ushort4*)(Out + (size_t)n * TWOJ + f0) =
            make_ushort4(f2b(re0), f2b(im0), f2b(re1), f2b(im1));
    }
}

// ---------------------------------------------------------------------------
// CSR build: histogram -> exclusive scan -> placement
// ---------------------------------------------------------------------------
__global__ __launch_bounds__(256) void hist_kernel(
    const int* __restrict__ src, const int* __restrict__ dst,
    int* __restrict__ deg, int E, int N)
{
    int e = blockIdx.x * 256 + threadIdx.x;
    if (e >= E) return;
    int s = src[e], d = dst[e];
    if ((unsigned)s >= (unsigned)N || (unsigned)d >= (unsigned)N) return;
    atomicAdd(&deg[d], 1);
}

__global__ __launch_bounds__(256) void scan1_kernel(
    const int* __restrict__ deg, int* __restrict__ row_off,
    int* __restrict__ partials, int N)
{
    __shared__ int sm[256];
    int i = blockIdx.x * 256 + threadIdx.x;
    int v = (i < N) ? deg[i] : 0;
    sm[threadIdx.x] = v;
    __syncthreads();
    #pragma unroll
    for (int o = 1; o < 256; o <<= 1) {
        int t = (threadIdx.x >= o) ? sm[threadIdx.x - o] : 0;
        __syncthreads();
        sm[threadIdx.x] += t;
        __syncthreads();
    }
    if (i < N) row_off[i] = sm[threadIdx.x] - v;
    if (threadIdx.x == 255) partials[blockIdx.x] = sm[255];
}

__global__ __launch_bounds__(512) void scan2_kernel(int* __restrict__ partials, int Nb)
{
    __shared__ int sm[512];
    int t = threadIdx.x;
    int v = (t < Nb) ? partials[t] : 0;
    sm[t] = v;
    __syncthreads();
    #pragma unroll
    for (int o = 1; o < 512; o <<= 1) {
        int x = (t >= o) ? sm[t - o] : 0;
        __syncthreads();
        sm[t] += x;
        __syncthreads();
    }
    if (t < Nb) partials[t] = sm[t] - v;
}

__global__ __launch_bounds__(256) void scan3_kernel(
    int* __restrict__ row_off, int* __restrict__ cursor,
    const int* __restrict__ partials, int N)
{
    int i = blockIdx.x * 256 + threadIdx.x;
    if (i >= N) return;
    int v = row_off[i] + partials[i >> 8];
    row_off[i] = v;
    cursor[i]  = v;
}

__global__ __launch_bounds__(256) void place_kernel(
    const int* __restrict__ src, const int* __restrict__ dst,
    int* __restrict__ cursor, int* __restrict__ csr_src, int E, int N)
{
    int e = blockIdx.x * 256 + threadIdx.x;
    if (e >= E) return;
    int s = src[e], d = dst[e];
    if ((unsigned)s >= (unsigned)N || (unsigned)d >= (unsigned)N) return;
    int pos = atomicAdd(&cursor[d], 1);
    csr_src[pos] = s;
}

// ---------------------------------------------------------------------------
// Gather-sum: agg[n] = sum_{e in CSR row n} h[src_e]   (bf16 rows)
// One wave per node; UPL = ushorts per lane (4 -> 512B rows, 2 -> 256B rows).
// 4-way edge unroll with independent accumulator banks for MLP.
// ---------------------------------------------------------------------------
template<int UPL>
__device__ __forceinline__ void ld_acc(const unsigned short* p, float* a) {
    if constexpr (UPL == 4) {
        ushort4 u = *(const ushort4*)p;
        a[0] += b2f(u.x); a[1] += b2f(u.y); a[2] += b2f(u.z); a[3] += b2f(u.w);
    } else {
        unsigned int u = *(const unsigned int*)p;
        a[0] += b2f((unsigned short)(u & 0xffffu));
        a[1] += b2f((unsigned short)(u >> 16));
    }
}

template<int UPL>
__global__ __launch_bounds__(256) void gather_kernel(
    const unsigned short* __restrict__ h, unsigned short* __restrict__ agg,
    const int* __restrict__ row_off, const int* __restrict__ deg,
    const int* __restrict__ csr_src, int N)
{
    constexpr int ROW = UPL * 64;
    int wid  = (blockIdx.x * 256 + threadIdx.x) >> 6;
    int lane = threadIdx.x & 63;
    if (wid >= N) return;
    int e   = row_off[wid];
    int end = e + deg[wid];

    float a0[UPL], a1[UPL], a2[UPL], a3[UPL];
    #pragma unroll
    for (int i = 0; i < UPL; ++i) { a0[i] = a1[i] = a2[i] = a3[i] = 0.f; }
    const unsigned short* hp = h + (size_t)lane * UPL;

    for (; e + 4 <= end; e += 4) {
        int s0 = csr_src[e],     s1 = csr_src[e + 1];
        int s2 = csr_src[e + 2], s3 = csr_src[e + 3];
        ld_acc<UPL>(hp + (size_t)s0 * ROW, a0);
        ld_acc<UPL>(hp + (size_t)s1 * ROW, a1);
        ld_acc<UPL>(hp + (size_t)s2 * ROW, a2);
        ld_acc<UPL>(hp + (size_t)s3 * ROW, a3);
    }
    for (; e < end; ++e)
        ld_acc<UPL>(hp + (size_t)csr_src[e] * ROW, a0);

    unsigned short* op = agg + (size_t)wid * ROW + lane * UPL;
    if constexpr (UPL == 4) {
        *(ushort4*)op = make_ushort4(
            f2b(a0[0] + a1[0] + a2[0] + a3[0]),
            f2b(a0[1] + a1[1] + a2[1] + a3[1]),
            f2b(a0[2] + a1[2] + a2[2] + a3[2]),
            f2b(a0[3] + a1[3] + a2[3] + a3[3]));
    } else {
        unsigned int pk = (unsigned int)f2b(a0[0] + a1[0] + a2[0] + a3[0])
                        | ((unsigned int)f2b(a0[1] + a1[1] + a2[1] + a3[1]) << 16);
        *(unsigned int*)op = pk;
    }
}

// ---------------------------------------------------------------------------
// abs + per-graph sum over final z [N,64]c bf16 (row = 128 ushorts).
// One wave per 16 consecutive nodes (batch sorted -> register run-accumulate).
// ---------------------------------------------------------------------------
__global__ __launch_bounds__(256) void abs_reduce_kernel(
    const unsigned short* __restrict__ z, const int* __restrict__ batch,
    float* __restrict__ sums, int N)
{
    constexpr int NPW = 16;
    int wid  = (blockIdx.x * 256 + threadIdx.x) >> 6;
    int lane = threadIdx.x & 63;
    int nBeg = wid * NPW;
    if (nBeg >= N) return;
    int nEnd = min(nBeg + NPW, N);

    float acc = 0.f;
    int cur_g = batch[nBeg];
    for (int n = nBeg; n < nEnd; ++n) {
        unsigned int u = *(const unsigned int*)(z + ((size_t)n << 7) + (lane << 1));
        float zr = b2f((unsigned short)(u & 0xffffu));
        float zi = b2f((unsigned short)(u >> 16));
        float a = sqrtf(zr * zr + zi * zi);
        int g = batch[n];
        if (g != cur_g) {
            if ((unsigned)cur_g < 64u) unsafeAtomicAdd(&sums[cur_g * 64 + lane], acc);
            acc = 0.f;
            cur_g = g;
        }
        acc += a;
    }
    if ((unsigned)cur_g < 64u) unsafeAtomicAdd(&sums[cur_g * 64 + lane], acc);
}

// per-graph count via binary search (batch sorted) + mean + log_softmax
__global__ __launch_bounds__(64) void finalize_kernel(
    const float* __restrict__ sums, const int* __restrict__ batch,
    float* __restrict__ out, int N)
{
    int g = blockIdx.x, d = threadIdx.x;
    __shared__ int cnt_s;
    if (d == 0) {
        int lo = 0, hi = N;
        while (lo < hi) { int mid = (lo + hi) >> 1; if (batch[mid] < g) lo = mid + 1; else hi = mid; }
        int lo2 = lo, hi2 = N;
        while (lo2 < hi2) { int mid = (lo2 + hi2) >> 1; if (batch[mid] < g + 1) lo2 = mid + 1; else hi2 = mid; }
        cnt_s = lo2 - lo;
    }
    __syncthreads();
    float c = fmaxf((float)cnt_s, 1.0f);
    float m = sums[g * 64 + d] / c;
    float mx = m;
    #pragma unroll
    for (int o = 32; o > 0; o >>= 1) mx = fmaxf(mx, __shfl_xor(mx, o, 64));
    float e = expf(m - mx);
    float s = e;
    #pragma unroll
    for (int o = 32; o > 0; o >>= 1) s += __shfl_xor(s, o, 64);
    out[g * 64 + d] = m - mx - logf(s);
}

extern "C" void kernel_launch(void* const* d_in, const int* in_sizes, int n_in,
                              void* d_out, int out_size, void* d_ws, size_t ws_size,
                              hipStream_t stream)
{
    const float* x   = (const float*)d_in[0];
    const float* W0r = (const float*)d_in[1];
    const float* W0i = (const float*)d_in[2];
    const float* b0r = (const float*)d_in[3];
    const float* b0i = (const float*)d_in[4];
    const float* M0r = (const float*)d_in[5];
    const float* M0i = (const float*)d_in[6];
    const float* c0r = (const float*)d_in[7];
    const float* c0i = (const float*)d_in[8];
    const float* t0r = (const float*)d_in[9];
    const float* t0i = (const float*)d_in[10];
    const float* W1r = (const float*)d_in[11];
    const float* W1i = (const float*)d_in[12];
    const float* b1r = (const float*)d_in[13];
    const float* b1i = (const float*)d_in[14];
    const float* M1r = (const float*)d_in[15];
    const float* M1i = (const float*)d_in[16];
    const float* c1r = (const float*)d_in[17];
    const float* c1i = (const float*)d_in[18];
    const float* t1r = (const float*)d_in[19];
    const float* t1i = (const float*)d_in[20];
    const int* edge  = (const int*)d_in[21];
    const int* batch = (const int*)d_in[22];

    const int N = in_sizes[0] / 128;
    const int E = in_sizes[21] / 2;
    const int* src = edge;
    const int* dst = edge + E;

    // ---- workspace (~174 MB) ----
    // h0/x1 [N,256]us | aggA [N,256]us | h1/z [N,128]us | aggB [N,128]us
    // | deg,row_off,cursor (N ints) | csr_src (E ints) | partial(512) | sums(4096 f32)
    unsigned short* h0   = (unsigned short*)d_ws;       // becomes x1 in place
    unsigned short* aggA = h0 + (size_t)N * 256;
    unsigned short* h1   = aggA + (size_t)N * 256;      // becomes z in place
    unsigned short* aggB = h1 + (size_t)N * 128;
    int*   deg     = (int*)(aggB + (size_t)N * 128);
    int*   row_off = deg + N;
    int*   cursor  = row_off + N;
    int*   csr_src = cursor + N;
    int*   partial = csr_src + E;
    float* sums    = (float*)(partial + 512);

    const int Nb = (N + 255) / 256;
    const int gemmGrid = (N + 63) / 64;
    const int edgeGrid = (E + 255) / 256;
    const int waveGrid = (N * 64 + 255) / 256;                 // wave/node
    const int wave16Grid = ((N + 15) / 16 * 64 + 255) / 256;   // wave/16 nodes

    // ---- CSR build ----
    hipMemsetAsync(deg, 0, N * sizeof(int), stream);
    hist_kernel<<<edgeGrid, 256, 0, stream>>>(src, dst, deg, E, N);
    scan1_kernel<<<Nb, 256, 0, stream>>>(deg, row_off, partial, N);
    scan2_kernel<<<1, 512, 0, stream>>>(partial, Nb);
    scan3_kernel<<<Nb, 256, 0, stream>>>(row_off, cursor, partial, N);
    place_kernel<<<edgeGrid, 256, 0, stream>>>(src, dst, cursor, csr_src, E, N);

    // ---- layer 0 ----
    // h0 = crelu(x @ W0^T + b0)
    mfma_cgemm_kernel<128,256,true,true,false><<<gemmGrid, 256, 0, stream>>>(
        x, W0r, W0i, b0r, b0i, nullptr, nullptr, nullptr, nullptr, h0, N);
    // aggA = sum h0[src]
    gather_kernel<4><<<waveGrid, 256, 0, stream>>>(
        h0, aggA, row_off, deg, csr_src, N);
    // x1 = ef*h0 + F*(aggA @ M0^T + deg*c0)   (in place over h0)
    mfma_cgemm_kernel<256,256,false,false,true><<<gemmGrid, 256, 0, stream>>>(
        aggA, M0r, M0i, c0r, c0i, t0r, t0i, h0, deg, h0, N);

    // ---- layer 1 ----
    // h1 = crelu(x1 @ W1^T + b1)
    mfma_cgemm_kernel<256,128,false,true,false><<<gemmGrid, 256, 0, stream>>>(
        h0, W1r, W1i, b1r, b1i, nullptr, nullptr, nullptr, nullptr, h1, N);
    // aggB = sum h1[src]
    gather_kernel<2><<<waveGrid, 256, 0, stream>>>(
        h1, aggB, row_off, deg, csr_src, N);
    // z = ef*h1 + F*(aggB @ M1^T + deg*c1)   (in place over h1)
    mfma_cgemm_kernel<128,128,false,false,true><<<gemmGrid, 256, 0, stream>>>(
        aggB, M1r, M1i, c1r, c1i, t1r, t1i, h1, deg, h1, N);

    // ---- readout ----
    hipMemsetAsync(sums, 0, 4096 * sizeof(float), stream);
    abs_reduce_kernel<<<wave16Grid, 256, 0, stream>>>(h1, batch, sums, N);
    finalize_kernel<<<64, 64, 0, stream>>>(sums, batch, (float*)d_out, N);
}

// Round 8
// 687.512 us; speedup vs baseline: 14.0690x; 1.0604x over previous
//
#include <hip/hip_runtime.h>

typedef __attribute__((ext_vector_type(8))) short bf16x8;
typedef __attribute__((ext_vector_type(4))) float f32x4;

// ---- bf16 (as ushort) helpers ----
__device__ __forceinline__ float b2f(unsigned short u) {
    return __uint_as_float(((unsigned int)u) << 16);
}
__device__ __forceinline__ unsigned short f2b(float f) {
    unsigned int u = __float_as_uint(f);
    unsigned int r = (u + 0x7FFFu + ((u >> 16) & 1u)) >> 16;   // RNE
    return (unsigned short)r;
}

// ---------------------------------------------------------------------------
// MFMA complex GEMM as real GEMM:  D[f][n] = sum_c V[f][c] * A[n][c]
// (unchanged from round 7 — see comments there)
// ---------------------------------------------------------------------------
template<int Kr, int TWOJ, bool REAL_IN, bool CRELU, bool MIX>
__global__ __launch_bounds__(256) void mfma_cgemm_kernel(
    const void* __restrict__ Xv,
    const float* __restrict__ Wr, const float* __restrict__ Wi,
    const float* __restrict__ br, const float* __restrict__ bi,
    const float* __restrict__ trp, const float* __restrict__ tip,
    const unsigned short* __restrict__ Hin, const int* __restrict__ degp,
    unsigned short* __restrict__ Out, int nNodes)
{
    constexpr int K      = REAL_IN ? Kr : Kr / 2;
    constexpr int TILES  = TWOJ / 16;
    constexpr int CHUNKS = Kr / 32;
    constexpr int VROW   = 40;

    __shared__ __align__(16) unsigned short sV[TWOJ * VROW];
    __shared__ __align__(16) unsigned short sA[64 * VROW];

    const int tid  = threadIdx.x;
    const int w    = tid >> 6;
    const int lane = tid & 63;
    const int l15  = lane & 15;
    const int q    = lane >> 4;
    const int n0   = blockIdx.x * 64;

    f32x4 acc[TILES];
    #pragma unroll
    for (int t = 0; t < TILES; ++t) acc[t] = (f32x4){0.f, 0.f, 0.f, 0.f};

    for (int kc = 0; kc < CHUNKS; ++kc) {
        if constexpr (REAL_IN) {
            #pragma unroll
            for (int it = 0; it < TWOJ * 8 / 256; ++it) {
                int idx = it * 256 + tid;
                int f  = idx >> 3;
                int cg = idx & 7;
                int j  = f >> 1;
                const float* wsrc = (f & 1) ? Wi : Wr;
                float4 v = *(const float4*)(wsrc + (size_t)j * K + kc * 32 + cg * 4);
                *(ushort4*)(sV + f * VROW + cg * 4) =
                    make_ushort4(f2b(v.x), f2b(v.y), f2b(v.z), f2b(v.w));
            }
        } else {
            #pragma unroll
            for (int it = 0; it < TWOJ * 8 / 256; ++it) {
                int idx = it * 256 + tid;
                int f  = idx >> 3;
                int cg = idx & 7;
                int j  = f >> 1;
                int k0 = kc * 16 + cg * 2;
                float2 wr2 = *(const float2*)(Wr + (size_t)j * K + k0);
                float2 wi2 = *(const float2*)(Wi + (size_t)j * K + k0);
                ushort4 u;
                if (f & 1) u = make_ushort4(f2b(wi2.x), f2b(wr2.x), f2b(wi2.y), f2b(wr2.y));
                else       u = make_ushort4(f2b(wr2.x), f2b(-wi2.x), f2b(wr2.y), f2b(-wi2.y));
                *(ushort4*)(sV + f * VROW + cg * 4) = u;
            }
        }
        if constexpr (REAL_IN) {
            const float* X = (const float*)Xv;
            #pragma unroll
            for (int it = 0; it < 2; ++it) {
                int idx = it * 256 + tid;
                int nl = idx >> 3;
                int cg = idx & 7;
                int n  = n0 + nl;
                float4 v = make_float4(0.f, 0.f, 0.f, 0.f);
                if (n < nNodes)
                    v = *(const float4*)(X + (size_t)n * Kr + kc * 32 + cg * 4);
                *(ushort4*)(sA + nl * VROW + cg * 4) =
                    make_ushort4(f2b(v.x), f2b(v.y), f2b(v.z), f2b(v.w));
            }
        } else {
            const unsigned short* X = (const unsigned short*)Xv;
            int nl = tid >> 2;
            int cg = tid & 3;
            int n  = n0 + nl;
            ushort4 a = make_ushort4(0,0,0,0), b = make_ushort4(0,0,0,0);
            if (n < nNodes) {
                const unsigned short* p = X + (size_t)n * Kr + kc * 32 + cg * 8;
                a = *(const ushort4*)(p);
                b = *(const ushort4*)(p + 4);
            }
            *(ushort4*)(sA + nl * VROW + cg * 8)     = a;
            *(ushort4*)(sA + nl * VROW + cg * 8 + 4) = b;
        }
        __syncthreads();

        bf16x8 bfrag = *(const bf16x8*)(sA + (w * 16 + l15) * VROW + q * 8);
        const unsigned short* vbase = sV + l15 * VROW + q * 8;
        #pragma unroll
        for (int t = 0; t < TILES; ++t) {
            bf16x8 afrag = *(const bf16x8*)(vbase + t * 16 * VROW);
            acc[t] = __builtin_amdgcn_mfma_f32_16x16x32_bf16(afrag, bfrag, acc[t], 0, 0, 0);
        }
        __syncthreads();
    }

    int n = n0 + w * 16 + l15;
    if (n >= nNodes) return;
    float Fr = 1.f, Fi = 0.f, efr = 1.f, efi = 0.f, dg = 0.f;
    if constexpr (MIX) {
        float tr = trp[0], ti = tip[0];
        float er  = expf(ti);
        float tfr =  er * cosf(tr);
        float tfi = -er * sinf(tr);
        float eh  = expf(0.5f * ti);
        efr =  eh * cosf(0.5f * tr);
        efi = -eh * sinf(0.5f * tr);
        float omr = 1.f - efr, omi = -efi;
        Fr = tfr * omr - tfi * omi;
        Fi = tfr * omi + tfi * omr;
        dg = (float)degp[n];
    }
    #pragma unroll
    for (int t = 0; t < TILES; ++t) {
        int f0 = t * 16 + q * 4;
        int j0 = f0 >> 1;
        float re0, im0, re1, im1;
        if constexpr (MIX) {
            float ar0 = acc[t][0] + dg * br[j0];
            float ai0 = acc[t][1] + dg * bi[j0];
            float ar1 = acc[t][2] + dg * br[j0 + 1];
            float ai1 = acc[t][3] + dg * bi[j0 + 1];
            re0 = ar0 * Fr - ai0 * Fi;  im0 = ar0 * Fi + ai0 * Fr;
            re1 = ar1 * Fr - ai1 * Fi;  im1 = ar1 * Fi + ai1 * Fr;
            ushort4 hu = *(const ushort4*)(Hin + (size_t)n * TWOJ + f0);
            float hr0 = b2f(hu.x), hi0 = b2f(hu.y), hr1 = b2f(hu.z), hi1 = b2f(hu.w);
            re0 += hr0 * efr - hi0 * efi;  im0 += hr0 * efi + hi0 * efr;
            re1 += hr1 * efr - hi1 * efi;  im1 += hr1 * efi + hi1 * efr;
        } else {
            re0 = acc[t][0] + br[j0];
            im0 = acc[t][1] + bi[j0];
            re1 = acc[t][2] + br[j0 + 1];
            im1 = acc[t][3] + bi[j0 + 1];
            if constexpr (CRELU) {
                re0 = fmaxf(re0, 0.f); im0 = fmaxf(im0, 0.f);
                re1 = fmaxf(re1, 0.f); im1 = fmaxf(im1, 0.f);
            }
        }
        *(ushort4*)(Out + (size_t)n * TWOJ + f0) =
            make_ushort4(f2b(re0), f2b(im0), f2b(re1), f2b(im1));
    }
}

// ---------------------------------------------------------------------------
// CSR build, XCD-partitioned: block b covers edge chunk (b>>3) and dst range
// (b&7) of 8. With round-robin blockIdx->XCD dispatch, each XCD's atomics and
// scatter stores stay inside a ~1/8 slice that lives in its own L2, so lines
// fill before write-back (round-7 place showed 105.9 MB WB = 1 line/store).
// Correctness does NOT depend on the mapping.
// ---------------------------------------------------------------------------
#define EDGE_CHUNK 2048

__global__ __launch_bounds__(256) void hist_kernel(
    const int* __restrict__ dst, int* __restrict__ deg, int E, int N)
{
    int x  = blockIdx.x & 7;
    int c  = blockIdx.x >> 3;
    int lo = (int)((long long)N * x / 8);
    int hi = (int)((long long)N * (x + 1) / 8);
    int base = c * EDGE_CHUNK;
    int end  = min(base + EDGE_CHUNK, E);
    for (int e = base + threadIdx.x; e < end; e += 256) {
        int d = dst[e];
        if (d >= lo && d < hi) atomicAdd(&deg[d], 1);
    }
}

__global__ __launch_bounds__(256) void place_kernel(
    const int* __restrict__ src, const int* __restrict__ dst,
    int* __restrict__ cursor, int* __restrict__ csr_src, int E, int N)
{
    int x  = blockIdx.x & 7;
    int c  = blockIdx.x >> 3;
    int lo = (int)((long long)N * x / 8);
    int hi = (int)((long long)N * (x + 1) / 8);
    int base = c * EDGE_CHUNK;
    int end  = min(base + EDGE_CHUNK, E);
    for (int e = base + threadIdx.x; e < end; e += 256) {
        int d = dst[e];
        if (d >= lo && d < hi) {
            int s = src[e];
            if ((unsigned)s < (unsigned)N) {
                int pos = atomicAdd(&cursor[d], 1);
                csr_src[pos] = s;
            }
        }
    }
}

__global__ __launch_bounds__(256) void scan1_kernel(
    const int* __restrict__ deg, int* __restrict__ row_off,
    int* __restrict__ partials, int N)
{
    __shared__ int sm[256];
    int i = blockIdx.x * 256 + threadIdx.x;
    int v = (i < N) ? deg[i] : 0;
    sm[threadIdx.x] = v;
    __syncthreads();
    #pragma unroll
    for (int o = 1; o < 256; o <<= 1) {
        int t = (threadIdx.x >= o) ? sm[threadIdx.x - o] : 0;
        __syncthreads();
        sm[threadIdx.x] += t;
        __syncthreads();
    }
    if (i < N) row_off[i] = sm[threadIdx.x] - v;
    if (threadIdx.x == 255) partials[blockIdx.x] = sm[255];
}

__global__ __launch_bounds__(512) void scan2_kernel(int* __restrict__ partials, int Nb)
{
    __shared__ int sm[512];
    int t = threadIdx.x;
    int v = (t < Nb) ? partials[t] : 0;
    sm[t] = v;
    __syncthreads();
    #pragma unroll
    for (int o = 1; o < 512; o <<= 1) {
        int x = (t >= o) ? sm[t - o] : 0;
        __syncthreads();
        sm[t] += x;
        __syncthreads();
    }
    if (t < Nb) partials[t] = sm[t] - v;
}

__global__ __launch_bounds__(256) void scan3_kernel(
    int* __restrict__ row_off, int* __restrict__ cursor,
    const int* __restrict__ partials, int N)
{
    int i = blockIdx.x * 256 + threadIdx.x;
    if (i >= N) return;
    int v = row_off[i] + partials[i >> 8];
    row_off[i] = v;
    cursor[i]  = v;
}

// ---------------------------------------------------------------------------
// Gather-sum: agg[n] = sum_{e in CSR row n} h[src_e]   (bf16 rows)
// One wave per node; UPL = ushorts per lane. 4-way edge unroll for MLP.
// ---------------------------------------------------------------------------
template<int UPL>
__device__ __forceinline__ void ld_acc(const unsigned short* p, float* a) {
    if constexpr (UPL == 4) {
        ushort4 u = *(const ushort4*)p;
        a[0] += b2f(u.x); a[1] += b2f(u.y); a[2] += b2f(u.z); a[3] += b2f(u.w);
    } else {
        unsigned int u = *(const unsigned int*)p;
        a[0] += b2f((unsigned short)(u & 0xffffu));
        a[1] += b2f((unsigned short)(u >> 16));
    }
}

template<int UPL>
__global__ __launch_bounds__(256) void gather_kernel(
    const unsigned short* __restrict__ h, unsigned short* __restrict__ agg,
    const int* __restrict__ row_off, const int* __restrict__ deg,
    const int* __restrict__ csr_src, int N)
{
    constexpr int ROW = UPL * 64;
    int wid  = (blockIdx.x * 256 + threadIdx.x) >> 6;
    int lane = threadIdx.x & 63;
    if (wid >= N) return;
    int e   = row_off[wid];
    int end = e + deg[wid];

    float a0[UPL], a1[UPL], a2[UPL], a3[UPL];
    #pragma unroll
    for (int i = 0; i < UPL; ++i) { a0[i] = a1[i] = a2[i] = a3[i] = 0.f; }
    const unsigned short* hp = h + (size_t)lane * UPL;

    for (; e + 4 <= end; e += 4) {
        int s0 = csr_src[e],     s1 = csr_src[e + 1];
        int s2 = csr_src[e + 2], s3 = csr_src[e + 3];
        ld_acc<UPL>(hp + (size_t)s0 * ROW, a0);
        ld_acc<UPL>(hp + (size_t)s1 * ROW, a1);
        ld_acc<UPL>(hp + (size_t)s2 * ROW, a2);
        ld_acc<UPL>(hp + (size_t)s3 * ROW, a3);
    }
    for (; e < end; ++e)
        ld_acc<UPL>(hp + (size_t)csr_src[e] * ROW, a0);

    unsigned short* op = agg + (size_t)wid * ROW + lane * UPL;
    if constexpr (UPL == 4) {
        *(ushort4*)op = make_ushort4(
            f2b(a0[0] + a1[0] + a2[0] + a3[0]),
            f2b(a0[1] + a1[1] + a2[1] + a3[1]),
            f2b(a0[2] + a1[2] + a2[2] + a3[2]),
            f2b(a0[3] + a1[3] + a2[3] + a3[3]));
    } else {
        unsigned int pk = (unsigned int)f2b(a0[0] + a1[0] + a2[0] + a3[0])
                        | ((unsigned int)f2b(a0[1] + a1[1] + a2[1] + a3[1]) << 16);
        *(unsigned int*)op = pk;
    }
}

// ---------------------------------------------------------------------------
// abs + per-graph sum over final z [N,64]c bf16 (row = 128 ushorts).
// ---------------------------------------------------------------------------
__global__ __launch_bounds__(256) void abs_reduce_kernel(
    const unsigned short* __restrict__ z, const int* __restrict__ batch,
    float* __restrict__ sums, int N)
{
    constexpr int NPW = 16;
    int wid  = (blockIdx.x * 256 + threadIdx.x) >> 6;
    int lane = threadIdx.x & 63;
    int nBeg = wid * NPW;
    if (nBeg >= N) return;
    int nEnd = min(nBeg + NPW, N);

    float acc = 0.f;
    int cur_g = batch[nBeg];
    for (int n = nBeg; n < nEnd; ++n) {
        unsigned int u = *(const unsigned int*)(z + ((size_t)n << 7) + (lane << 1));
        float zr = b2f((unsigned short)(u & 0xffffu));
        float zi = b2f((unsigned short)(u >> 16));
        float a = sqrtf(zr * zr + zi * zi);
        int g = batch[n];
        if (g != cur_g) {
            if ((unsigned)cur_g < 64u) unsafeAtomicAdd(&sums[cur_g * 64 + lane], acc);
            acc = 0.f;
            cur_g = g;
        }
        acc += a;
    }
    if ((unsigned)cur_g < 64u) unsafeAtomicAdd(&sums[cur_g * 64 + lane], acc);
}

// per-graph count via binary search (batch sorted) + mean + log_softmax
__global__ __launch_bounds__(64) void finalize_kernel(
    const float* __restrict__ sums, const int* __restrict__ batch,
    float* __restrict__ out, int N)
{
    int g = blockIdx.x, d = threadIdx.x;
    __shared__ int cnt_s;
    if (d == 0) {
        int lo = 0, hi = N;
        while (lo < hi) { int mid = (lo + hi) >> 1; if (batch[mid] < g) lo = mid + 1; else hi = mid; }
        int lo2 = lo, hi2 = N;
        while (lo2 < hi2) { int mid = (lo2 + hi2) >> 1; if (batch[mid] < g + 1) lo2 = mid + 1; else hi2 = mid; }
        cnt_s = lo2 - lo;
    }
    __syncthreads();
    float c = fmaxf((float)cnt_s, 1.0f);
    float m = sums[g * 64 + d] / c;
    float mx = m;
    #pragma unroll
    for (int o = 32; o > 0; o >>= 1) mx = fmaxf(mx, __shfl_xor(mx, o, 64));
    float e = expf(m - mx);
    float s = e;
    #pragma unroll
    for (int o = 32; o > 0; o >>= 1) s += __shfl_xor(s, o, 64);
    out[g * 64 + d] = m - mx - logf(s);
}

extern "C" void kernel_launch(void* const* d_in, const int* in_sizes, int n_in,
                              void* d_out, int out_size, void* d_ws, size_t ws_size,
                              hipStream_t stream)
{
    const float* x   = (const float*)d_in[0];
    const float* W0r = (const float*)d_in[1];
    const float* W0i = (const float*)d_in[2];
    const float* b0r = (const float*)d_in[3];
    const float* b0i = (const float*)d_in[4];
    const float* M0r = (const float*)d_in[5];
    const float* M0i = (const float*)d_in[6];
    const float* c0r = (const float*)d_in[7];
    const float* c0i = (const float*)d_in[8];
    const float* t0r = (const float*)d_in[9];
    const float* t0i = (const float*)d_in[10];
    const float* W1r = (const float*)d_in[11];
    const float* W1i = (const float*)d_in[12];
    const float* b1r = (const float*)d_in[13];
    const float* b1i = (const float*)d_in[14];
    const float* M1r = (const float*)d_in[15];
    const float* M1i = (const float*)d_in[16];
    const float* c1r = (const float*)d_in[17];
    const float* c1i = (const float*)d_in[18];
    const float* t1r = (const float*)d_in[19];
    const float* t1i = (const float*)d_in[20];
    const int* edge  = (const int*)d_in[21];
    const int* batch = (const int*)d_in[22];

    const int N = in_sizes[0] / 128;
    const int E = in_sizes[21] / 2;
    const int* src = edge;
    const int* dst = edge + E;

    // ---- workspace (~174 MB) ----
    unsigned short* h0   = (unsigned short*)d_ws;       // becomes x1 in place
    unsigned short* aggA = h0 + (size_t)N * 256;
    unsigned short* h1   = aggA + (size_t)N * 256;      // becomes z in place
    unsigned short* aggB = h1 + (size_t)N * 128;
    int*   deg     = (int*)(aggB + (size_t)N * 128);
    int*   row_off = deg + N;
    int*   cursor  = row_off + N;
    int*   csr_src = cursor + N;
    int*   partial = csr_src + E;
    float* sums    = (float*)(partial + 512);

    const int Nb = (N + 255) / 256;
    const int gemmGrid = (N + 63) / 64;
    const int xcdEdgeGrid = ((E + EDGE_CHUNK - 1) / EDGE_CHUNK) * 8;
    const int waveGrid = (N * 64 + 255) / 256;
    const int wave16Grid = ((N + 15) / 16 * 64 + 255) / 256;

    // ---- CSR build (XCD-partitioned edge passes) ----
    hipMemsetAsync(deg, 0, N * sizeof(int), stream);
    hist_kernel<<<xcdEdgeGrid, 256, 0, stream>>>(dst, deg, E, N);
    scan1_kernel<<<Nb, 256, 0, stream>>>(deg, row_off, partial, N);
    scan2_kernel<<<1, 512, 0, stream>>>(partial, Nb);
    scan3_kernel<<<Nb, 256, 0, stream>>>(row_off, cursor, partial, N);
    place_kernel<<<xcdEdgeGrid, 256, 0, stream>>>(src, dst, cursor, csr_src, E, N);

    // ---- layer 0 ----
    mfma_cgemm_kernel<128,256,true,true,false><<<gemmGrid, 256, 0, stream>>>(
        x, W0r, W0i, b0r, b0i, nullptr, nullptr, nullptr, nullptr, h0, N);
    gather_kernel<4><<<waveGrid, 256, 0, stream>>>(
        h0, aggA, row_off, deg, csr_src, N);
    mfma_cgemm_kernel<256,256,false,false,true><<<gemmGrid, 256, 0, stream>>>(
        aggA, M0r, M0i, c0r, c0i, t0r, t0i, h0, deg, h0, N);

    // ---- layer 1 ----
    mfma_cgemm_kernel<256,128,false,true,false><<<gemmGrid, 256, 0, stream>>>(
        h0, W1r, W1i, b1r, b1i, nullptr, nullptr, nullptr, nullptr, h1, N);
    gather_kernel<2><<<waveGrid, 256, 0, stream>>>(
        h1, aggB, row_off, deg, csr_src, N);
    mfma_cgemm_kernel<128,128,false,false,true><<<gemmGrid, 256, 0, stream>>>(
        aggB, M1r, M1i, c1r, c1i, t1r, t1i, h1, deg, h1, N);

    // ---- readout ----
    hipMemsetAsync(sums, 0, 4096 * sizeof(float), stream);
    abs_reduce_kernel<<<wave16Grid, 256, 0, stream>>>(h1, batch, sums, N);
    finalize_kernel<<<64, 64, 0, stream>>>(sums, batch, (float*)d_out, N);
}

// Round 9
// 676.016 us; speedup vs baseline: 14.3083x; 1.0170x over previous
//
#include <hip/hip_runtime.h>

typedef __attribute__((ext_vector_type(8))) short bf16x8;
typedef __attribute__((ext_vector_type(4))) float f32x4;

// ---- bf16 (as ushort) helpers ----
__device__ __forceinline__ float b2f(unsigned short u) {
    return __uint_as_float(((unsigned int)u) << 16);
}
__device__ __forceinline__ unsigned short f2b(float f) {
    unsigned int u = __float_as_uint(f);
    unsigned int r = (u + 0x7FFFu + ((u >> 16) & 1u)) >> 16;   // RNE
    return (unsigned short)r;
}

// ---------------------------------------------------------------------------
// MFMA complex GEMM as real GEMM:  D[f][n] = sum_c V[f][c] * A[n][c]
// (unchanged from round 7 — see comments there)
// ---------------------------------------------------------------------------
template<int Kr, int TWOJ, bool REAL_IN, bool CRELU, bool MIX>
__global__ __launch_bounds__(256) void mfma_cgemm_kernel(
    const void* __restrict__ Xv,
    const float* __restrict__ Wr, const float* __restrict__ Wi,
    const float* __restrict__ br, const float* __restrict__ bi,
    const float* __restrict__ trp, const float* __restrict__ tip,
    const unsigned short* __restrict__ Hin, const int* __restrict__ degp,
    unsigned short* __restrict__ Out, int nNodes)
{
    constexpr int K      = REAL_IN ? Kr : Kr / 2;
    constexpr int TILES  = TWOJ / 16;
    constexpr int CHUNKS = Kr / 32;
    constexpr int VROW   = 40;

    __shared__ __align__(16) unsigned short sV[TWOJ * VROW];
    __shared__ __align__(16) unsigned short sA[64 * VROW];

    const int tid  = threadIdx.x;
    const int w    = tid >> 6;
    const int lane = tid & 63;
    const int l15  = lane & 15;
    const int q    = lane >> 4;
    const int n0   = blockIdx.x * 64;

    f32x4 acc[TILES];
    #pragma unroll
    for (int t = 0; t < TILES; ++t) acc[t] = (f32x4){0.f, 0.f, 0.f, 0.f};

    for (int kc = 0; kc < CHUNKS; ++kc) {
        if constexpr (REAL_IN) {
            #pragma unroll
            for (int it = 0; it < TWOJ * 8 / 256; ++it) {
                int idx = it * 256 + tid;
                int f  = idx >> 3;
                int cg = idx & 7;
                int j  = f >> 1;
                const float* wsrc = (f & 1) ? Wi : Wr;
                float4 v = *(const float4*)(wsrc + (size_t)j * K + kc * 32 + cg * 4);
                *(ushort4*)(sV + f * VROW + cg * 4) =
                    make_ushort4(f2b(v.x), f2b(v.y), f2b(v.z), f2b(v.w));
            }
        } else {
            #pragma unroll
            for (int it = 0; it < TWOJ * 8 / 256; ++it) {
                int idx = it * 256 + tid;
                int f  = idx >> 3;
                int cg = idx & 7;
                int j  = f >> 1;
                int k0 = kc * 16 + cg * 2;
                float2 wr2 = *(const float2*)(Wr + (size_t)j * K + k0);
                float2 wi2 = *(const float2*)(Wi + (size_t)j * K + k0);
                ushort4 u;
                if (f & 1) u = make_ushort4(f2b(wi2.x), f2b(wr2.x), f2b(wi2.y), f2b(wr2.y));
                else       u = make_ushort4(f2b(wr2.x), f2b(-wi2.x), f2b(wr2.y), f2b(-wi2.y));
                *(ushort4*)(sV + f * VROW + cg * 4) = u;
            }
        }
        if constexpr (REAL_IN) {
            const float* X = (const float*)Xv;
            #pragma unroll
            for (int it = 0; it < 2; ++it) {
                int idx = it * 256 + tid;
                int nl = idx >> 3;
                int cg = idx & 7;
                int n  = n0 + nl;
                float4 v = make_float4(0.f, 0.f, 0.f, 0.f);
                if (n < nNodes)
                    v = *(const float4*)(X + (size_t)n * Kr + kc * 32 + cg * 4);
                *(ushort4*)(sA + nl * VROW + cg * 4) =
                    make_ushort4(f2b(v.x), f2b(v.y), f2b(v.z), f2b(v.w));
            }
        } else {
            const unsigned short* X = (const unsigned short*)Xv;
            int nl = tid >> 2;
            int cg = tid & 3;
            int n  = n0 + nl;
            ushort4 a = make_ushort4(0,0,0,0), b = make_ushort4(0,0,0,0);
            if (n < nNodes) {
                const unsigned short* p = X + (size_t)n * Kr + kc * 32 + cg * 8;
                a = *(const ushort4*)(p);
                b = *(const ushort4*)(p + 4);
            }
            *(ushort4*)(sA + nl * VROW + cg * 8)     = a;
            *(ushort4*)(sA + nl * VROW + cg * 8 + 4) = b;
        }
        __syncthreads();

        bf16x8 bfrag = *(const bf16x8*)(sA + (w * 16 + l15) * VROW + q * 8);
        const unsigned short* vbase = sV + l15 * VROW + q * 8;
        #pragma unroll
        for (int t = 0; t < TILES; ++t) {
            bf16x8 afrag = *(const bf16x8*)(vbase + t * 16 * VROW);
            acc[t] = __builtin_amdgcn_mfma_f32_16x16x32_bf16(afrag, bfrag, acc[t], 0, 0, 0);
        }
        __syncthreads();
    }

    int n = n0 + w * 16 + l15;
    if (n >= nNodes) return;
    float Fr = 1.f, Fi = 0.f, efr = 1.f, efi = 0.f, dg = 0.f;
    if constexpr (MIX) {
        float tr = trp[0], ti = tip[0];
        float er  = expf(ti);
        float tfr =  er * cosf(tr);
        float tfi = -er * sinf(tr);
        float eh  = expf(0.5f * ti);
        efr =  eh * cosf(0.5f * tr);
        efi = -eh * sinf(0.5f * tr);
        float omr = 1.f - efr, omi = -efi;
        Fr = tfr * omr - tfi * omi;
        Fi = tfr * omi + tfi * omr;
        dg = (float)degp[n];
    }
    #pragma unroll
    for (int t = 0; t < TILES; ++t) {
        int f0 = t * 16 + q * 4;
        int j0 = f0 >> 1;
        float re0, im0, re1, im1;
        if constexpr (MIX) {
            float ar0 = acc[t][0] + dg * br[j0];
            float ai0 = acc[t][1] + dg * bi[j0];
            float ar1 = acc[t][2] + dg * br[j0 + 1];
            float ai1 = acc[t][3] + dg * bi[j0 + 1];
            re0 = ar0 * Fr - ai0 * Fi;  im0 = ar0 * Fi + ai0 * Fr;
            re1 = ar1 * Fr - ai1 * Fi;  im1 = ar1 * Fi + ai1 * Fr;
            ushort4 hu = *(const ushort4*)(Hin + (size_t)n * TWOJ + f0);
            float hr0 = b2f(hu.x), hi0 = b2f(hu.y), hr1 = b2f(hu.z), hi1 = b2f(hu.w);
            re0 += hr0 * efr - hi0 * efi;  im0 += hr0 * efi + hi0 * efr;
            re1 += hr1 * efr - hi1 * efi;  im1 += hr1 * efi + hi1 * efr;
        } else {
            re0 = acc[t][0] + br[j0];
            im0 = acc[t][1] + bi[j0];
            re1 = acc[t][2] + br[j0 + 1];
            im1 = acc[t][3] + bi[j0 + 1];
            if constexpr (CRELU) {
                re0 = fmaxf(re0, 0.f); im0 = fmaxf(im0, 0.f);
                re1 = fmaxf(re1, 0.f); im1 = fmaxf(im1, 0.f);
            }
        }
        *(ushort4*)(Out + (size_t)n * TWOJ + f0) =
            make_ushort4(f2b(re0), f2b(im0), f2b(re1), f2b(im1));
    }
}

// ---------------------------------------------------------------------------
// CSR build, XCD-partitioned (see round 8 comments).
// ---------------------------------------------------------------------------
#define EDGE_CHUNK 2048

__global__ __launch_bounds__(256) void hist_kernel(
    const int* __restrict__ dst, int* __restrict__ deg, int E, int N)
{
    int x  = blockIdx.x & 7;
    int c  = blockIdx.x >> 3;
    int lo = (int)((long long)N * x / 8);
    int hi = (int)((long long)N * (x + 1) / 8);
    int base = c * EDGE_CHUNK;
    int end  = min(base + EDGE_CHUNK, E);
    for (int e = base + threadIdx.x; e < end; e += 256) {
        int d = dst[e];
        if (d >= lo && d < hi) atomicAdd(&deg[d], 1);
    }
}

__global__ __launch_bounds__(256) void place_kernel(
    const int* __restrict__ src, const int* __restrict__ dst,
    int* __restrict__ cursor, int* __restrict__ csr_src, int E, int N)
{
    int x  = blockIdx.x & 7;
    int c  = blockIdx.x >> 3;
    int lo = (int)((long long)N * x / 8);
    int hi = (int)((long long)N * (x + 1) / 8);
    int base = c * EDGE_CHUNK;
    int end  = min(base + EDGE_CHUNK, E);
    for (int e = base + threadIdx.x; e < end; e += 256) {
        int d = dst[e];
        if (d >= lo && d < hi) {
            int s = src[e];
            if ((unsigned)s < (unsigned)N) {
                int pos = atomicAdd(&cursor[d], 1);
                csr_src[pos] = s;
            }
        }
    }
}

__global__ __launch_bounds__(256) void scan1_kernel(
    const int* __restrict__ deg, int* __restrict__ row_off,
    int* __restrict__ partials, int N)
{
    __shared__ int sm[256];
    int i = blockIdx.x * 256 + threadIdx.x;
    int v = (i < N) ? deg[i] : 0;
    sm[threadIdx.x] = v;
    __syncthreads();
    #pragma unroll
    for (int o = 1; o < 256; o <<= 1) {
        int t = (threadIdx.x >= o) ? sm[threadIdx.x - o] : 0;
        __syncthreads();
        sm[threadIdx.x] += t;
        __syncthreads();
    }
    if (i < N) row_off[i] = sm[threadIdx.x] - v;
    if (threadIdx.x == 255) partials[blockIdx.x] = sm[255];
}

__global__ __launch_bounds__(512) void scan2_kernel(int* __restrict__ partials, int Nb)
{
    __shared__ int sm[512];
    int t = threadIdx.x;
    int v = (t < Nb) ? partials[t] : 0;
    sm[t] = v;
    __syncthreads();
    #pragma unroll
    for (int o = 1; o < 512; o <<= 1) {
        int x = (t >= o) ? sm[t - o] : 0;
        __syncthreads();
        sm[t] += x;
        __syncthreads();
    }
    if (t < Nb) partials[t] = sm[t] - v;
}

__global__ __launch_bounds__(256) void scan3_kernel(
    int* __restrict__ row_off, int* __restrict__ cursor,
    const int* __restrict__ partials, int N)
{
    int i = blockIdx.x * 256 + threadIdx.x;
    if (i >= N) return;
    int v = row_off[i] + partials[i >> 8];
    row_off[i] = v;
    cursor[i]  = v;
}

// ---------------------------------------------------------------------------
// Gather-sum: agg[n] = sum_{e in CSR row n} h[src_e]   (bf16 rows)
// Split-wave: each lane loads 16 B (8 bf16); LPR = ROW/8 lanes cover one row,
// so one wave-instruction fetches R = 64/LPR rows. 4-way unroll -> 4R rows
// in flight. Cross-subrow combine via shfl_xor at the end.
// ROW = ushorts per row (256 for layer 0, 128 for layer 1).
// ---------------------------------------------------------------------------
template<int ROW>
__global__ __launch_bounds__(256) void gather_kernel(
    const unsigned short* __restrict__ h, unsigned short* __restrict__ agg,
    const int* __restrict__ row_off, const int* __restrict__ deg,
    const int* __restrict__ csr_src, int N)
{
    constexpr int LPR = ROW / 8;     // lanes per row
    constexpr int R   = 64 / LPR;    // rows per wave-load
    int wid  = (blockIdx.x * 256 + threadIdx.x) >> 6;
    int lane = threadIdx.x & 63;
    if (wid >= N) return;
    const int subrow = lane / LPR;
    const int fofs   = (lane % LPR) * 8;   // ushort offset within row
    int e   = row_off[wid];
    int end = e + deg[wid];

    float a[4][8];
    #pragma unroll
    for (int u = 0; u < 4; ++u)
        #pragma unroll
        for (int k = 0; k < 8; ++k) a[u][k] = 0.f;

    const unsigned short* hp = h + fofs;

    // accumulate uint4 (8 bf16) into bank: low half = <<16, high half = mask
    #define ACC_U4(bank, uu)                                                    \
        {                                                                       \
            a[bank][0] += __uint_as_float((uu).x << 16);                        \
            a[bank][1] += __uint_as_float((uu).x & 0xffff0000u);                \
            a[bank][2] += __uint_as_float((uu).y << 16);                        \
            a[bank][3] += __uint_as_float((uu).y & 0xffff0000u);                \
            a[bank][4] += __uint_as_float((uu).z << 16);                        \
            a[bank][5] += __uint_as_float((uu).z & 0xffff0000u);                \
            a[bank][6] += __uint_as_float((uu).w << 16);                        \
            a[bank][7] += __uint_as_float((uu).w & 0xffff0000u);                \
        }

    for (; e + 4 * R <= end; e += 4 * R) {
        int s0 = csr_src[e + 0 * R + subrow];
        int s1 = csr_src[e + 1 * R + subrow];
        int s2 = csr_src[e + 2 * R + subrow];
        int s3 = csr_src[e + 3 * R + subrow];
        uint4 u0 = *(const uint4*)(hp + (size_t)s0 * ROW);
        uint4 u1 = *(const uint4*)(hp + (size_t)s1 * ROW);
        uint4 u2 = *(const uint4*)(hp + (size_t)s2 * ROW);
        uint4 u3 = *(const uint4*)(hp + (size_t)s3 * ROW);
        ACC_U4(0, u0) ACC_U4(1, u1) ACC_U4(2, u2) ACC_U4(3, u3)
    }
    for (; e < end; e += R) {
        int idx = e + subrow;
        if (idx < end) {
            int s = csr_src[idx];
            uint4 u = *(const uint4*)(hp + (size_t)s * ROW);
            ACC_U4(0, u)
        }
    }
    #undef ACC_U4

    float r[8];
    #pragma unroll
    for (int k = 0; k < 8; ++k) {
        r[k] = a[0][k] + a[1][k] + a[2][k] + a[3][k];
        if (R >= 2) r[k] += __shfl_xor(r[k], 32, 64);
        if (R >= 4) r[k] += __shfl_xor(r[k], 16, 64);
    }
    if (subrow == 0) {
        unsigned short* op = agg + (size_t)wid * ROW + fofs;
        *(ushort4*)(op)     = make_ushort4(f2b(r[0]), f2b(r[1]), f2b(r[2]), f2b(r[3]));
        *(ushort4*)(op + 4) = make_ushort4(f2b(r[4]), f2b(r[5]), f2b(r[6]), f2b(r[7]));
    }
}

// ---------------------------------------------------------------------------
// abs + per-graph sum over final z [N,64]c bf16 (row = 128 ushorts).
// ---------------------------------------------------------------------------
__global__ __launch_bounds__(256) void abs_reduce_kernel(
    const unsigned short* __restrict__ z, const int* __restrict__ batch,
    float* __restrict__ sums, int N)
{
    constexpr int NPW = 16;
    int wid  = (blockIdx.x * 256 + threadIdx.x) >> 6;
    int lane = threadIdx.x & 63;
    int nBeg = wid * NPW;
    if (nBeg >= N) return;
    int nEnd = min(nBeg + NPW, N);

    float acc = 0.f;
    int cur_g = batch[nBeg];
    for (int n = nBeg; n < nEnd; ++n) {
        unsigned int u = *(const unsigned int*)(z + ((size_t)n << 7) + (lane << 1));
        float zr = b2f((unsigned short)(u & 0xffffu));
        float zi = b2f((unsigned short)(u >> 16));
        float a = sqrtf(zr * zr + zi * zi);
        int g = batch[n];
        if (g != cur_g) {
            if ((unsigned)cur_g < 64u) unsafeAtomicAdd(&sums[cur_g * 64 + lane], acc);
            acc = 0.f;
            cur_g = g;
        }
        acc += a;
    }
    if ((unsigned)cur_g < 64u) unsafeAtomicAdd(&sums[cur_g * 64 + lane], acc);
}

// per-graph count via binary search (batch sorted) + mean + log_softmax
__global__ __launch_bounds__(64) void finalize_kernel(
    const float* __restrict__ sums, const int* __restrict__ batch,
    float* __restrict__ out, int N)
{
    int g = blockIdx.x, d = threadIdx.x;
    __shared__ int cnt_s;
    if (d == 0) {
        int lo = 0, hi = N;
        while (lo < hi) { int mid = (lo + hi) >> 1; if (batch[mid] < g) lo = mid + 1; else hi = mid; }
        int lo2 = lo, hi2 = N;
        while (lo2 < hi2) { int mid = (lo2 + hi2) >> 1; if (batch[mid] < g + 1) lo2 = mid + 1; else hi2 = mid; }
        cnt_s = lo2 - lo;
    }
    __syncthreads();
    float c = fmaxf((float)cnt_s, 1.0f);
    float m = sums[g * 64 + d] / c;
    float mx = m;
    #pragma unroll
    for (int o = 32; o > 0; o >>= 1) mx = fmaxf(mx, __shfl_xor(mx, o, 64));
    float e = expf(m - mx);
    float s = e;
    #pragma unroll
    for (int o = 32; o > 0; o >>= 1) s += __shfl_xor(s, o, 64);
    out[g * 64 + d] = m - mx - logf(s);
}

extern "C" void kernel_launch(void* const* d_in, const int* in_sizes, int n_in,
                              void* d_out, int out_size, void* d_ws, size_t ws_size,
                              hipStream_t stream)
{
    const float* x   = (const float*)d_in[0];
    const float* W0r = (const float*)d_in[1];
    const float* W0i = (const float*)d_in[2];
    const float* b0r = (const float*)d_in[3];
    const float* b0i = (const float*)d_in[4];
    const float* M0r = (const float*)d_in[5];
    const float* M0i = (const float*)d_in[6];
    const float* c0r = (const float*)d_in[7];
    const float* c0i = (const float*)d_in[8];
    const float* t0r = (const float*)d_in[9];
    const float* t0i = (const float*)d_in[10];
    const float* W1r = (const float*)d_in[11];
    const float* W1i = (const float*)d_in[12];
    const float* b1r = (const float*)d_in[13];
    const float* b1i = (const float*)d_in[14];
    const float* M1r = (const float*)d_in[15];
    const float* M1i = (const float*)d_in[16];
    const float* c1r = (const float*)d_in[17];
    const float* c1i = (const float*)d_in[18];
    const float* t1r = (const float*)d_in[19];
    const float* t1i = (const float*)d_in[20];
    const int* edge  = (const int*)d_in[21];
    const int* batch = (const int*)d_in[22];

    const int N = in_sizes[0] / 128;
    const int E = in_sizes[21] / 2;
    const int* src = edge;
    const int* dst = edge + E;

    // ---- workspace (~174 MB) ----
    unsigned short* h0   = (unsigned short*)d_ws;       // becomes x1 in place
    unsigned short* aggA = h0 + (size_t)N * 256;
    unsigned short* h1   = aggA + (size_t)N * 256;      // becomes z in place
    unsigned short* aggB = h1 + (size_t)N * 128;
    int*   deg     = (int*)(aggB + (size_t)N * 128);
    int*   row_off = deg + N;
    int*   cursor  = row_off + N;
    int*   csr_src = cursor + N;
    int*   partial = csr_src + E;
    float* sums    = (float*)(partial + 512);

    const int Nb = (N + 255) / 256;
    const int gemmGrid = (N + 63) / 64;
    const int xcdEdgeGrid = ((E + EDGE_CHUNK - 1) / EDGE_CHUNK) * 8;
    const int waveGrid = (N * 64 + 255) / 256;
    const int wave16Grid = ((N + 15) / 16 * 64 + 255) / 256;

    // ---- CSR build (XCD-partitioned edge passes) ----
    hipMemsetAsync(deg, 0, N * sizeof(int), stream);
    hist_kernel<<<xcdEdgeGrid, 256, 0, stream>>>(dst, deg, E, N);
    scan1_kernel<<<Nb, 256, 0, stream>>>(deg, row_off, partial, N);
    scan2_kernel<<<1, 512, 0, stream>>>(partial, Nb);
    scan3_kernel<<<Nb, 256, 0, stream>>>(row_off, cursor, partial, N);
    place_kernel<<<xcdEdgeGrid, 256, 0, stream>>>(src, dst, cursor, csr_src, E, N);

    // ---- layer 0 ----
    mfma_cgemm_kernel<128,256,true,true,false><<<gemmGrid, 256, 0, stream>>>(
        x, W0r, W0i, b0r, b0i, nullptr, nullptr, nullptr, nullptr, h0, N);
    gather_kernel<256><<<waveGrid, 256, 0, stream>>>(
        h0, aggA, row_off, deg, csr_src, N);
    mfma_cgemm_kernel<256,256,false,false,true><<<gemmGrid, 256, 0, stream>>>(
        aggA, M0r, M0i, c0r, c0i, t0r, t0i, h0, deg, h0, N);

    // ---- layer 1 ----
    mfma_cgemm_kernel<256,128,false,true,false><<<gemmGrid, 256, 0, stream>>>(
        h0, W1r, W1i, b1r, b1i, nullptr, nullptr, nullptr, nullptr, h1, N);
    gather_kernel<128><<<waveGrid, 256, 0, stream>>>(
        h1, aggB, row_off, deg, csr_src, N);
    mfma_cgemm_kernel<128,128,false,false,true><<<gemmGrid, 256, 0, stream>>>(
        aggB, M1r, M1i, c1r, c1i, t1r, t1i, h1, deg, h1, N);

    // ---- readout ----
    hipMemsetAsync(sums, 0, 4096 * sizeof(float), stream);
    abs_reduce_kernel<<<wave16Grid, 256, 0, stream>>>(h1, batch, sums, N);
    finalize_kernel<<<64, 64, 0, stream>>>(sums, batch, (float*)d_out, N);
}